// Round 4
// baseline (1376.279 us; speedup 1.0000x reference)
//
#include <hip/hip_runtime.h>
#include <stdint.h>
#include <math.h>

#define T_STEPS 4096
#define BATCH   256
#define NB_BLK  256      // T/16 spike blocks per chain

// LIF step, threshold=1:  v'=alpha*v+xs; s=max(floor(v'),0); v=v'-s
// Identity: v_new = min(v', fract(v')); s = v' - v_new (exact fp32).
// Invariant: post-step v < 1.  Zero-input step is exactly v *= alpha.
__device__ __forceinline__ float lif_step(float& v, float xs, float alpha) {
    float vp = fmaf(alpha, v, xs);
    float fr = vp - floorf(vp);
    float vn = fminf(vp, fr);
    float s  = vp - vn;
    v = vn;
    return s;
}

__device__ __forceinline__ float ubf(uint32_t w, int k) {
    return (float)((w >> (k * 8)) & 0xffu);
}

// ---------------------------------------------------------------------------
// seg1: one 1024-thread block per batch b.
//  (a) zeroes its PRIVATE slices of out / bm1 / bm2 / flags (no cross-block race)
//      out slice = 4096*10 floats = 10240 float4  ->  10 passes of 1024 threads
//      (R3 bug: 40 passes = 4x OOB -> abort)
//  (b) thread (co, seg) computes layer-1 y on the fly for its 64-step segment
//      and certifies "no spike possible": zero-start response acc_j plus
//      worst-case carry-in alpha^(j+1)*v_start (v_start < 1 always).
//      bound < 0.999 for all segments & channels  =>  s1 == 0 exactly.
// ---------------------------------------------------------------------------
__global__ __launch_bounds__(1024) void seg1(
    const float* __restrict__ x, const float* __restrict__ w1,
    float* __restrict__ out, uint8_t* __restrict__ bm1, uint8_t* __restrict__ bm2,
    uint8_t* __restrict__ flag1, uint8_t* __restrict__ flag2,
    float alpha, float one_m)
{
    const int tid = threadIdx.x;
    const int b   = blockIdx.x;

    // ---- zero per-batch slices --------------------------------------------
    float4* o4 = (float4*)(out + (size_t)b * T_STEPS * 10);   // 10240 float4
    float4 z4 = make_float4(0.f, 0.f, 0.f, 0.f);
#pragma unroll
    for (int i = 0; i < 10; ++i) o4[i * 1024 + tid] = z4;     // exactly 10240
    if (tid < 16)
        ((uint4*)(bm1 + (size_t)b * NB_BLK))[tid] = make_uint4(0u,0u,0u,0u);
    else if (tid < 32)
        ((uint4*)(bm2 + (size_t)b * NB_BLK))[tid - 16] = make_uint4(0u,0u,0u,0u);
    else if (tid == 32) { flag1[b] = 0; flag2[b] = 0; }
    __syncthreads();

    // ---- segmented certification ------------------------------------------
    const int co  = tid & 15;      // wave = 16 co x 4 segments -> broadcast rows
    const int seg = tid >> 4;      // 0..63

    float wr[16];
#pragma unroll
    for (int i = 0; i < 16; ++i) wr[i] = one_m * w1[co * 16 + i];

    const float4* xp = (const float4*)(x + ((size_t)b * T_STEPS + (size_t)seg * 64) * 16);

    float acc = 0.0f, bound = -1e30f, pw = alpha;
    float4 c0 = xp[0], c1 = xp[1], c2 = xp[2], c3 = xp[3];
    for (int j = 0; j < 64; ++j) {
        float4 d0 = c0, d1 = c1, d2 = c2, d3 = c3;
        int jn = (j < 63) ? j + 1 : 63;
        c0 = xp[jn * 4 + 0]; c1 = xp[jn * 4 + 1];
        c2 = xp[jn * 4 + 2]; c3 = xp[jn * 4 + 3];

        float p0 = fmaf(wr[1], d0.y, wr[0] * d0.x);
        p0 = fmaf(wr[2], d0.z, p0);  p0 = fmaf(wr[3], d0.w, p0);
        float p1 = fmaf(wr[5], d1.y, wr[4] * d1.x);
        p1 = fmaf(wr[6], d1.z, p1);  p1 = fmaf(wr[7], d1.w, p1);
        float p2 = fmaf(wr[9], d2.y, wr[8] * d2.x);
        p2 = fmaf(wr[10], d2.z, p2); p2 = fmaf(wr[11], d2.w, p2);
        float p3 = fmaf(wr[13], d3.y, wr[12] * d3.x);
        p3 = fmaf(wr[14], d3.z, p3); p3 = fmaf(wr[15], d3.w, p3);
        float y = (p0 + p1) + (p2 + p3);

        acc   = fmaf(alpha, acc, y);       // zero-start response
        bound = fmaxf(bound, acc + pw);    // + alpha^(j+1) * max v_start
        pw   *= alpha;
    }
    if (bound >= 0.999f) flag1[b] = 1;     // benign same-value race
}

// ---------------------------------------------------------------------------
// fb1: exact serial fallback for flagged batches (normally all threads exit).
// Writes s1t[b][c][t] bytes + bm1 bits for the whole batch. Arithmetic is
// bit-identical to the round-1 validated fused kernel.
// ---------------------------------------------------------------------------
__global__ __launch_bounds__(64) void fb1(
    const float* __restrict__ x, const float* __restrict__ w1,
    uint8_t* __restrict__ s1t, uint8_t* __restrict__ bm1,
    const uint8_t* __restrict__ flag1, float alpha, float one_m)
{
    const int co = threadIdx.x & 15;
    const int b  = blockIdx.x * 4 + (threadIdx.x >> 4);
    if (!flag1[b]) return;

    float wr[16];
#pragma unroll
    for (int i = 0; i < 16; ++i) wr[i] = one_m * w1[co * 16 + i];

    const float4* xp = (const float4*)(x + (size_t)b * T_STEPS * 16);
    uint8_t* op  = s1t + ((size_t)b * 16 + co) * T_STEPS;
    uint8_t* bmp = bm1 + (size_t)b * NB_BLK;

    float v = 0.0f;
    for (int t = 0; t < T_STEPS; ++t) {
        float4 c0 = xp[t*4+0], c1 = xp[t*4+1], c2 = xp[t*4+2], c3 = xp[t*4+3];
        float p0 = fmaf(wr[1], c0.y, wr[0] * c0.x);
        p0 = fmaf(wr[2], c0.z, p0);  p0 = fmaf(wr[3], c0.w, p0);
        float p1 = fmaf(wr[5], c1.y, wr[4] * c1.x);
        p1 = fmaf(wr[6], c1.z, p1);  p1 = fmaf(wr[7], c1.w, p1);
        float p2 = fmaf(wr[9], c2.y, wr[8] * c2.x);
        p2 = fmaf(wr[10], c2.z, p2); p2 = fmaf(wr[11], c2.w, p2);
        float p3 = fmaf(wr[13], c3.y, wr[12] * c3.x);
        p3 = fmaf(wr[14], c3.z, p3); p3 = fmaf(wr[15], c3.w, p3);
        float xs = (p0 + p1) + (p2 + p3);
        float s = lif_step(v, xs, alpha);
        op[t] = (uint8_t)(int)s;
        if (s != 0.0f) bmp[t >> 4] = 1;
    }
}

// ---------------- layer-2: sparse scan, s1t -> s2t + bitmap2 ----------------
__global__ __launch_bounds__(64) void scan2(const uint8_t* __restrict__ s1t,
        const float* __restrict__ w2, uint8_t* __restrict__ s2t,
        const uint8_t* __restrict__ bm1, uint8_t* __restrict__ bm2,
        const uint8_t* __restrict__ flag1, uint8_t* __restrict__ flag2,
        float alpha, float one_m)
{
    const int tid = threadIdx.x;
    const int co  = tid & 31;
    const int b   = blockIdx.x * 2 + (tid >> 5);
    if (!flag1[b]) return;   // no layer-1 spikes in this batch -> all zero

    float wr[16];
#pragma unroll
    for (int i = 0; i < 16; ++i) wr[i] = one_m * w2[co * 16 + i];

    const uint8_t* sbase = s1t + (size_t)b * 16 * T_STEPS;
    uint4* op = (uint4*)(s2t + ((size_t)b * 32 + co) * T_STEPS);
    const uint4* bmv = (const uint4*)(bm1 + (size_t)b * NB_BLK);
    uint8_t* bm2p = bm2 + (size_t)b * NB_BLK;

    float v = 0.0f;
    for (int sb = 0; sb < 16; ++sb) {
        uint4 bm = bmv[sb];
        if ((bm.x | bm.y | bm.z | bm.w) == 0u) {
            if (v != 0.0f) {
                for (int blk = 0; blk < 16 && v != 0.0f; ++blk) {
#pragma unroll
                    for (int j = 0; j < 16; ++j) v *= alpha;
                }
            }
            continue;
        }
        for (int blk = 0; blk < 16; ++blk) {
            uint32_t d = (blk < 4) ? bm.x : (blk < 8) ? bm.y
                       : (blk < 12) ? bm.z : bm.w;
            uint32_t byte = (d >> ((blk & 3) * 8)) & 0xffu;
            if (byte == 0u) {
                if (v != 0.0f) {
#pragma unroll
                    for (int j = 0; j < 16; ++j) v *= alpha;
                }
                continue;
            }
            const int tb = sb * 16 + blk;
            const int t0 = tb * 16;
            uint4 S[16];
#pragma unroll
            for (int c = 0; c < 16; ++c)
                S[c] = *(const uint4*)(sbase + (size_t)c * T_STEPS + t0);
            uint32_t w[4] = {0u, 0u, 0u, 0u};
#pragma unroll
            for (int j = 0; j < 16; ++j) {
                float xv[16];
#pragma unroll
                for (int c = 0; c < 16; ++c) {
                    uint32_t dd = (j < 4) ? S[c].x : (j < 8) ? S[c].y
                                : (j < 12) ? S[c].z : S[c].w;
                    xv[c] = ubf(dd, j & 3);
                }
                float p0 = fmaf(wr[1], xv[1], wr[0] * xv[0]);
                p0 = fmaf(wr[2], xv[2], p0);   p0 = fmaf(wr[3], xv[3], p0);
                float p1 = fmaf(wr[5], xv[5], wr[4] * xv[4]);
                p1 = fmaf(wr[6], xv[6], p1);   p1 = fmaf(wr[7], xv[7], p1);
                float p2 = fmaf(wr[9], xv[9], wr[8] * xv[8]);
                p2 = fmaf(wr[10], xv[10], p2); p2 = fmaf(wr[11], xv[11], p2);
                float p3 = fmaf(wr[13], xv[13], wr[12] * xv[12]);
                p3 = fmaf(wr[14], xv[14], p3); p3 = fmaf(wr[15], xv[15], p3);
                float xs = (p0 + p1) + (p2 + p3);
                float s = lif_step(v, xs, alpha);
                w[j >> 2] |= ((uint32_t)(int)s) << ((j & 3) * 8);
            }
            op[tb] = make_uint4(w[0], w[1], w[2], w[3]);
            if (w[0] | w[1] | w[2] | w[3]) { bm2p[tb] = 1; flag2[b] = 1; }
        }
    }
}

// ---------------- layer-3: sparse scan, s2t -> out[b,t,10] (pre-zeroed) -----
__global__ __launch_bounds__(64) void scan3(const uint8_t* __restrict__ s2t,
        const float* __restrict__ w3, float* __restrict__ out,
        const uint8_t* __restrict__ bm2, const uint8_t* __restrict__ flag2,
        float alpha, float one_m)
{
    const int tid = threadIdx.x;
    const int co  = tid & 15;           // 10 active
    const int b   = blockIdx.x * 4 + (tid >> 4);
    if (!flag2[b]) return;   // no layer-2 spikes in this batch -> out stays 0
    const bool active = (co < 10);

    float wr[32];
#pragma unroll
    for (int i = 0; i < 32; ++i) wr[i] = active ? (one_m * w3[co * 32 + i]) : 0.0f;

    const uint8_t* sbase = s2t + (size_t)b * 32 * T_STEPS;
    const uint4* bmv = (const uint4*)(bm2 + (size_t)b * NB_BLK);
    float* ob = out + (size_t)b * T_STEPS * 10 + co;

    float v = 0.0f;
    for (int sb = 0; sb < 16; ++sb) {
        uint4 bm = bmv[sb];
        if ((bm.x | bm.y | bm.z | bm.w) == 0u) {
            if (v != 0.0f) {
                for (int blk = 0; blk < 16 && v != 0.0f; ++blk) {
#pragma unroll
                    for (int j = 0; j < 16; ++j) v *= alpha;
                }
            }
            continue;
        }
        for (int blk = 0; blk < 16; ++blk) {
            uint32_t d = (blk < 4) ? bm.x : (blk < 8) ? bm.y
                       : (blk < 12) ? bm.z : bm.w;
            uint32_t byte = (d >> ((blk & 3) * 8)) & 0xffu;
            if (byte == 0u) {
                if (v != 0.0f) {
#pragma unroll
                    for (int j = 0; j < 16; ++j) v *= alpha;
                }
                continue;
            }
            const int t0 = (sb * 16 + blk) * 16;
            uint4 S[32];
#pragma unroll
            for (int c = 0; c < 32; ++c)
                S[c] = *(const uint4*)(sbase + (size_t)c * T_STEPS + t0);
#pragma unroll
            for (int j = 0; j < 16; ++j) {
                float xv[32];
#pragma unroll
                for (int c = 0; c < 32; ++c) {
                    uint32_t dd = (j < 4) ? S[c].x : (j < 8) ? S[c].y
                                : (j < 12) ? S[c].z : S[c].w;
                    xv[c] = ubf(dd, j & 3);
                }
                float p0 = fmaf(wr[1], xv[1], wr[0] * xv[0]);
                p0 = fmaf(wr[2],  xv[2],  p0); p0 = fmaf(wr[3],  xv[3],  p0);
                p0 = fmaf(wr[4],  xv[4],  p0); p0 = fmaf(wr[5],  xv[5],  p0);
                p0 = fmaf(wr[6],  xv[6],  p0); p0 = fmaf(wr[7],  xv[7],  p0);
                float p1 = fmaf(wr[9], xv[9], wr[8] * xv[8]);
                p1 = fmaf(wr[10], xv[10], p1); p1 = fmaf(wr[11], xv[11], p1);
                p1 = fmaf(wr[12], xv[12], p1); p1 = fmaf(wr[13], xv[13], p1);
                p1 = fmaf(wr[14], xv[14], p1); p1 = fmaf(wr[15], xv[15], p1);
                float p2 = fmaf(wr[17], xv[17], wr[16] * xv[16]);
                p2 = fmaf(wr[18], xv[18], p2); p2 = fmaf(wr[19], xv[19], p2);
                p2 = fmaf(wr[20], xv[20], p2); p2 = fmaf(wr[21], xv[21], p2);
                p2 = fmaf(wr[22], xv[22], p2); p2 = fmaf(wr[23], xv[23], p2);
                float p3 = fmaf(wr[25], xv[25], wr[24] * xv[24]);
                p3 = fmaf(wr[26], xv[26], p3); p3 = fmaf(wr[27], xv[27], p3);
                p3 = fmaf(wr[28], xv[28], p3); p3 = fmaf(wr[29], xv[29], p3);
                p3 = fmaf(wr[30], xv[30], p3); p3 = fmaf(wr[31], xv[31], p3);
                float xs = (p0 + p1) + (p2 + p3);
                float s = lif_step(v, xs, alpha);
                if (active && s != 0.0f) ob[(size_t)(t0 + j) * 10] = s;
            }
        }
    }
}

extern "C" void kernel_launch(void* const* d_in, const int* in_sizes, int n_in,
                              void* d_out, int out_size, void* d_ws, size_t ws_size,
                              hipStream_t stream)
{
    const float* data = (const float*)d_in[0];
    const float* w1   = (const float*)d_in[1];
    const float* w2   = (const float*)d_in[2];
    const float* w3   = (const float*)d_in[3];
    float* out = (float*)d_out;

    // ws layout (48 MiB + 128 KiB + 512 B):
    //   [0, 16M)    s1t  u8 [256][16][4096]   (written only by fb1, read via bm1)
    //   [16M, 48M)  s2t  u8 [256][32][4096]   (written only where bm2 set)
    //   [48M, ..)   bm1 64K | bm2 64K | flag1 256 | flag2 256
    uint8_t* ws    = (uint8_t*)d_ws;
    uint8_t* s1t   = ws;
    uint8_t* s2t   = ws + (16u << 20);
    uint8_t* bm1   = ws + (48u << 20);
    uint8_t* bm2   = bm1 + (64u << 10);
    uint8_t* flag1 = bm2 + (64u << 10);
    uint8_t* flag2 = flag1 + 256;

    const float alpha = expf(-1.0f / 20.0f);
    const float one_m = 1.0f - alpha;

    seg1 <<<BATCH,     1024, 0, stream>>>(data, w1, out, bm1, bm2, flag1, flag2,
                                          alpha, one_m);
    fb1  <<<BATCH / 4,   64, 0, stream>>>(data, w1, s1t, bm1, flag1, alpha, one_m);
    scan2<<<BATCH / 2,   64, 0, stream>>>(s1t, w2, s2t, bm1, bm2, flag1, flag2,
                                          alpha, one_m);
    scan3<<<BATCH / 4,   64, 0, stream>>>(s2t, w3, out, bm2, flag2, alpha, one_m);
}

// Round 5
// 1329.325 us; speedup vs baseline: 1.0353x; 1.0353x over previous
//
#include <hip/hip_runtime.h>
#include <stdint.h>
#include <math.h>

#define T_STEPS 4096
#define BATCH   256
#define NB_BLK  256      // T/16 spike blocks per chain

// LIF step, threshold=1:  v'=alpha*v+xs; s=max(floor(v'),0); v=v'-s
// Identity: v_new = min(v', fract(v')); s = v' - v_new (exact fp32).
// Invariant: post-step v < 1.  Zero-input step is exactly v *= alpha.
__device__ __forceinline__ float lif_step(float& v, float xs, float alpha) {
    float vp = fmaf(alpha, v, xs);
    float fr = vp - floorf(vp);
    float vn = fminf(vp, fr);
    float s  = vp - vn;
    v = vn;
    return s;
}

__device__ __forceinline__ float ubf(uint32_t w, int k) {
    return (float)((w >> (k * 8)) & 0xffu);
}

// ---------------------------------------------------------------------------
// seg1: one 1024-thread block per batch b = (co 0..15) x (seg 0..63).
//  (a) zeroes PRIVATE slices of out / bm1 / bm2 (no cross-block race)
//  (b) each thread runs its 64-step segment of the LINEAR (no-spike) model:
//        acc_j  : zero-start response (same fma sequence as fb1 -> bit-match)
//        M0     = max_j acc_j                 (segment max if carry-in = 0)
//        M1     = max_j (acc_j + alpha^(j+1)) (segment max if carry-in = 1)
//        acc_end: segment-final zero-start value
//  (c) 16 threads serially compose actual boundary values
//        vs <- fma(alpha^64, vs, acc_end)  over 64 segments,
//      and certify each segment via convexity of f(vs)=max_j(acc_j+a^(j+1)vs):
//        f(vs) <= (1-vs+)*M0 + vs+*M1,  vs+ = clamp(vs+1e-3, 0, 1).
//      bound < 0.999 everywhere  =>  layer-1 spikes are impossible (margin
//      1e-3 >> ~1e-5 fp32 composition drift)  =>  s1 == 0 exactly.
//      Otherwise flag the batch for the exact serial fallback fb1.
// ---------------------------------------------------------------------------
__global__ __launch_bounds__(1024) void seg1(
    const float* __restrict__ x, const float* __restrict__ w1,
    float* __restrict__ out, uint8_t* __restrict__ bm1, uint8_t* __restrict__ bm2,
    uint8_t* __restrict__ flag1, uint8_t* __restrict__ flag2,
    float alpha, float one_m, float alpha64)
{
    const int tid = threadIdx.x;
    const int b   = blockIdx.x;

    __shared__ float sh_end[64][16];
    __shared__ float sh_m0[64][16];
    __shared__ float sh_m1[64][16];
    __shared__ int   sh_flag;

    // ---- zero per-batch slices --------------------------------------------
    float4* o4 = (float4*)(out + (size_t)b * T_STEPS * 10);   // 10240 float4
    float4 z4 = make_float4(0.f, 0.f, 0.f, 0.f);
#pragma unroll
    for (int i = 0; i < 10; ++i) o4[i * 1024 + tid] = z4;     // exactly 10240
    if (tid < 16)
        ((uint4*)(bm1 + (size_t)b * NB_BLK))[tid] = make_uint4(0u,0u,0u,0u);
    else if (tid < 32)
        ((uint4*)(bm2 + (size_t)b * NB_BLK))[tid - 16] = make_uint4(0u,0u,0u,0u);
    else if (tid == 32) { flag2[b] = 0; sh_flag = 0; }

    // ---- per-segment linear response + maxima -----------------------------
    const int co  = tid & 15;      // wave = 16 co x 4 segments -> broadcast rows
    const int seg = tid >> 4;      // 0..63

    float wr[16];
#pragma unroll
    for (int i = 0; i < 16; ++i) wr[i] = one_m * w1[co * 16 + i];

    const float4* xp = (const float4*)(x + ((size_t)b * T_STEPS + (size_t)seg * 64) * 16);

    float acc = 0.0f, m0 = -1e30f, m1 = -1e30f, pw = alpha;
    float4 c0 = xp[0], c1 = xp[1], c2 = xp[2], c3 = xp[3];
    for (int j = 0; j < 64; ++j) {
        float4 d0 = c0, d1 = c1, d2 = c2, d3 = c3;
        int jn = (j < 63) ? j + 1 : 63;
        c0 = xp[jn * 4 + 0]; c1 = xp[jn * 4 + 1];
        c2 = xp[jn * 4 + 2]; c3 = xp[jn * 4 + 3];

        float p0 = fmaf(wr[1], d0.y, wr[0] * d0.x);
        p0 = fmaf(wr[2], d0.z, p0);  p0 = fmaf(wr[3], d0.w, p0);
        float p1 = fmaf(wr[5], d1.y, wr[4] * d1.x);
        p1 = fmaf(wr[6], d1.z, p1);  p1 = fmaf(wr[7], d1.w, p1);
        float p2 = fmaf(wr[9], d2.y, wr[8] * d2.x);
        p2 = fmaf(wr[10], d2.z, p2); p2 = fmaf(wr[11], d2.w, p2);
        float p3 = fmaf(wr[13], d3.y, wr[12] * d3.x);
        p3 = fmaf(wr[14], d3.z, p3); p3 = fmaf(wr[15], d3.w, p3);
        float y = (p0 + p1) + (p2 + p3);

        acc = fmaf(alpha, acc, y);         // zero-start response acc_j
        m0  = fmaxf(m0, acc);
        m1  = fmaxf(m1, acc + pw);         // + alpha^(j+1) * 1
        pw *= alpha;
    }
    sh_end[seg][co] = acc;
    sh_m0[seg][co]  = m0;
    sh_m1[seg][co]  = m1;
    __syncthreads();

    // ---- serial composition + certification (16 threads, 64 steps) --------
    if (tid < 16) {
        const int c = tid;
        float vs = 0.0f;
        int bad = 0;
        for (int s = 0; s < 64; ++s) {
            float vsu = fminf(fmaxf(vs + 1e-3f, 0.0f), 1.0f);
            float bound = fmaf(1.0f - vsu, sh_m0[s][c], vsu * sh_m1[s][c]);
            bad |= (bound >= 0.999f);
            vs = fmaf(alpha64, vs, sh_end[s][c]);
        }
        if (bad) atomicOr(&sh_flag, 1);
    }
    __syncthreads();
    if (tid == 0) flag1[b] = (uint8_t)sh_flag;
}

// ---------------------------------------------------------------------------
// fb1: exact serial fallback for flagged batches (normally all threads exit).
// Writes s1t[b][c][t] bytes + bm1 bits for the whole batch. Arithmetic is
// bit-identical to the round-1 validated fused kernel.
// ---------------------------------------------------------------------------
__global__ __launch_bounds__(64) void fb1(
    const float* __restrict__ x, const float* __restrict__ w1,
    uint8_t* __restrict__ s1t, uint8_t* __restrict__ bm1,
    const uint8_t* __restrict__ flag1, float alpha, float one_m)
{
    const int co = threadIdx.x & 15;
    const int b  = blockIdx.x * 4 + (threadIdx.x >> 4);
    if (!flag1[b]) return;

    float wr[16];
#pragma unroll
    for (int i = 0; i < 16; ++i) wr[i] = one_m * w1[co * 16 + i];

    const float4* xp = (const float4*)(x + (size_t)b * T_STEPS * 16);
    uint8_t* op  = s1t + ((size_t)b * 16 + co) * T_STEPS;
    uint8_t* bmp = bm1 + (size_t)b * NB_BLK;

    float v = 0.0f;
    for (int t = 0; t < T_STEPS; ++t) {
        float4 c0 = xp[t*4+0], c1 = xp[t*4+1], c2 = xp[t*4+2], c3 = xp[t*4+3];
        float p0 = fmaf(wr[1], c0.y, wr[0] * c0.x);
        p0 = fmaf(wr[2], c0.z, p0);  p0 = fmaf(wr[3], c0.w, p0);
        float p1 = fmaf(wr[5], c1.y, wr[4] * c1.x);
        p1 = fmaf(wr[6], c1.z, p1);  p1 = fmaf(wr[7], c1.w, p1);
        float p2 = fmaf(wr[9], c2.y, wr[8] * c2.x);
        p2 = fmaf(wr[10], c2.z, p2); p2 = fmaf(wr[11], c2.w, p2);
        float p3 = fmaf(wr[13], c3.y, wr[12] * c3.x);
        p3 = fmaf(wr[14], c3.z, p3); p3 = fmaf(wr[15], c3.w, p3);
        float xs = (p0 + p1) + (p2 + p3);
        float s = lif_step(v, xs, alpha);
        op[t] = (uint8_t)(int)s;
        if (s != 0.0f) bmp[t >> 4] = 1;
    }
}

// ---------------- layer-2: sparse scan, s1t -> s2t + bitmap2 ----------------
__global__ __launch_bounds__(64) void scan2(const uint8_t* __restrict__ s1t,
        const float* __restrict__ w2, uint8_t* __restrict__ s2t,
        const uint8_t* __restrict__ bm1, uint8_t* __restrict__ bm2,
        const uint8_t* __restrict__ flag1, uint8_t* __restrict__ flag2,
        float alpha, float one_m)
{
    const int tid = threadIdx.x;
    const int co  = tid & 31;
    const int b   = blockIdx.x * 2 + (tid >> 5);
    if (!flag1[b]) return;   // no layer-1 spikes in this batch -> all zero

    float wr[16];
#pragma unroll
    for (int i = 0; i < 16; ++i) wr[i] = one_m * w2[co * 16 + i];

    const uint8_t* sbase = s1t + (size_t)b * 16 * T_STEPS;
    uint4* op = (uint4*)(s2t + ((size_t)b * 32 + co) * T_STEPS);
    const uint4* bmv = (const uint4*)(bm1 + (size_t)b * NB_BLK);
    uint8_t* bm2p = bm2 + (size_t)b * NB_BLK;

    float v = 0.0f;
    for (int sb = 0; sb < 16; ++sb) {
        uint4 bm = bmv[sb];
        if ((bm.x | bm.y | bm.z | bm.w) == 0u) {
            if (v != 0.0f) {
                for (int blk = 0; blk < 16 && v != 0.0f; ++blk) {
#pragma unroll
                    for (int j = 0; j < 16; ++j) v *= alpha;
                }
            }
            continue;
        }
        for (int blk = 0; blk < 16; ++blk) {
            uint32_t d = (blk < 4) ? bm.x : (blk < 8) ? bm.y
                       : (blk < 12) ? bm.z : bm.w;
            uint32_t byte = (d >> ((blk & 3) * 8)) & 0xffu;
            if (byte == 0u) {
                if (v != 0.0f) {
#pragma unroll
                    for (int j = 0; j < 16; ++j) v *= alpha;
                }
                continue;
            }
            const int tb = sb * 16 + blk;
            const int t0 = tb * 16;
            uint4 S[16];
#pragma unroll
            for (int c = 0; c < 16; ++c)
                S[c] = *(const uint4*)(sbase + (size_t)c * T_STEPS + t0);
            uint32_t w[4] = {0u, 0u, 0u, 0u};
#pragma unroll
            for (int j = 0; j < 16; ++j) {
                float xv[16];
#pragma unroll
                for (int c = 0; c < 16; ++c) {
                    uint32_t dd = (j < 4) ? S[c].x : (j < 8) ? S[c].y
                                : (j < 12) ? S[c].z : S[c].w;
                    xv[c] = ubf(dd, j & 3);
                }
                float p0 = fmaf(wr[1], xv[1], wr[0] * xv[0]);
                p0 = fmaf(wr[2], xv[2], p0);   p0 = fmaf(wr[3], xv[3], p0);
                float p1 = fmaf(wr[5], xv[5], wr[4] * xv[4]);
                p1 = fmaf(wr[6], xv[6], p1);   p1 = fmaf(wr[7], xv[7], p1);
                float p2 = fmaf(wr[9], xv[9], wr[8] * xv[8]);
                p2 = fmaf(wr[10], xv[10], p2); p2 = fmaf(wr[11], xv[11], p2);
                float p3 = fmaf(wr[13], xv[13], wr[12] * xv[12]);
                p3 = fmaf(wr[14], xv[14], p3); p3 = fmaf(wr[15], xv[15], p3);
                float xs = (p0 + p1) + (p2 + p3);
                float s = lif_step(v, xs, alpha);
                w[j >> 2] |= ((uint32_t)(int)s) << ((j & 3) * 8);
            }
            op[tb] = make_uint4(w[0], w[1], w[2], w[3]);
            if (w[0] | w[1] | w[2] | w[3]) { bm2p[tb] = 1; flag2[b] = 1; }
        }
    }
}

// ---------------- layer-3: sparse scan, s2t -> out[b,t,10] (pre-zeroed) -----
__global__ __launch_bounds__(64) void scan3(const uint8_t* __restrict__ s2t,
        const float* __restrict__ w3, float* __restrict__ out,
        const uint8_t* __restrict__ bm2, const uint8_t* __restrict__ flag2,
        float alpha, float one_m)
{
    const int tid = threadIdx.x;
    const int co  = tid & 15;           // 10 active
    const int b   = blockIdx.x * 4 + (tid >> 4);
    if (!flag2[b]) return;   // no layer-2 spikes in this batch -> out stays 0
    const bool active = (co < 10);

    float wr[32];
#pragma unroll
    for (int i = 0; i < 32; ++i) wr[i] = active ? (one_m * w3[co * 32 + i]) : 0.0f;

    const uint8_t* sbase = s2t + (size_t)b * 32 * T_STEPS;
    const uint4* bmv = (const uint4*)(bm2 + (size_t)b * NB_BLK);
    float* ob = out + (size_t)b * T_STEPS * 10 + co;

    float v = 0.0f;
    for (int sb = 0; sb < 16; ++sb) {
        uint4 bm = bmv[sb];
        if ((bm.x | bm.y | bm.z | bm.w) == 0u) {
            if (v != 0.0f) {
                for (int blk = 0; blk < 16 && v != 0.0f; ++blk) {
#pragma unroll
                    for (int j = 0; j < 16; ++j) v *= alpha;
                }
            }
            continue;
        }
        for (int blk = 0; blk < 16; ++blk) {
            uint32_t d = (blk < 4) ? bm.x : (blk < 8) ? bm.y
                       : (blk < 12) ? bm.z : bm.w;
            uint32_t byte = (d >> ((blk & 3) * 8)) & 0xffu;
            if (byte == 0u) {
                if (v != 0.0f) {
#pragma unroll
                    for (int j = 0; j < 16; ++j) v *= alpha;
                }
                continue;
            }
            const int t0 = (sb * 16 + blk) * 16;
            uint4 S[32];
#pragma unroll
            for (int c = 0; c < 32; ++c)
                S[c] = *(const uint4*)(sbase + (size_t)c * T_STEPS + t0);
#pragma unroll
            for (int j = 0; j < 16; ++j) {
                float xv[32];
#pragma unroll
                for (int c = 0; c < 32; ++c) {
                    uint32_t dd = (j < 4) ? S[c].x : (j < 8) ? S[c].y
                                : (j < 12) ? S[c].z : S[c].w;
                    xv[c] = ubf(dd, j & 3);
                }
                float p0 = fmaf(wr[1], xv[1], wr[0] * xv[0]);
                p0 = fmaf(wr[2],  xv[2],  p0); p0 = fmaf(wr[3],  xv[3],  p0);
                p0 = fmaf(wr[4],  xv[4],  p0); p0 = fmaf(wr[5],  xv[5],  p0);
                p0 = fmaf(wr[6],  xv[6],  p0); p0 = fmaf(wr[7],  xv[7],  p0);
                float p1 = fmaf(wr[9], xv[9], wr[8] * xv[8]);
                p1 = fmaf(wr[10], xv[10], p1); p1 = fmaf(wr[11], xv[11], p1);
                p1 = fmaf(wr[12], xv[12], p1); p1 = fmaf(wr[13], xv[13], p1);
                p1 = fmaf(wr[14], xv[14], p1); p1 = fmaf(wr[15], xv[15], p1);
                float p2 = fmaf(wr[17], xv[17], wr[16] * xv[16]);
                p2 = fmaf(wr[18], xv[18], p2); p2 = fmaf(wr[19], xv[19], p2);
                p2 = fmaf(wr[20], xv[20], p2); p2 = fmaf(wr[21], xv[21], p2);
                p2 = fmaf(wr[22], xv[22], p2); p2 = fmaf(wr[23], xv[23], p2);
                float p3 = fmaf(wr[25], xv[25], wr[24] * xv[24]);
                p3 = fmaf(wr[26], xv[26], p3); p3 = fmaf(wr[27], xv[27], p3);
                p3 = fmaf(wr[28], xv[28], p3); p3 = fmaf(wr[29], xv[29], p3);
                p3 = fmaf(wr[30], xv[30], p3); p3 = fmaf(wr[31], xv[31], p3);
                float xs = (p0 + p1) + (p2 + p3);
                float s = lif_step(v, xs, alpha);
                if (active && s != 0.0f) ob[(size_t)(t0 + j) * 10] = s;
            }
        }
    }
}

extern "C" void kernel_launch(void* const* d_in, const int* in_sizes, int n_in,
                              void* d_out, int out_size, void* d_ws, size_t ws_size,
                              hipStream_t stream)
{
    const float* data = (const float*)d_in[0];
    const float* w1   = (const float*)d_in[1];
    const float* w2   = (const float*)d_in[2];
    const float* w3   = (const float*)d_in[3];
    float* out = (float*)d_out;

    // ws layout (48 MiB + 128 KiB + 512 B):
    //   [0, 16M)    s1t  u8 [256][16][4096]   (written only by fb1, read via bm1)
    //   [16M, 48M)  s2t  u8 [256][32][4096]   (written only where bm2 set)
    //   [48M, ..)   bm1 64K | bm2 64K | flag1 256 | flag2 256
    uint8_t* ws    = (uint8_t*)d_ws;
    uint8_t* s1t   = ws;
    uint8_t* s2t   = ws + (16u << 20);
    uint8_t* bm1   = ws + (48u << 20);
    uint8_t* bm2   = bm1 + (64u << 10);
    uint8_t* flag1 = bm2 + (64u << 10);
    uint8_t* flag2 = flag1 + 256;

    const float alpha   = expf(-1.0f / 20.0f);
    const float one_m   = 1.0f - alpha;
    const float alpha64 = expf(-64.0f / 20.0f);

    seg1 <<<BATCH,     1024, 0, stream>>>(data, w1, out, bm1, bm2, flag1, flag2,
                                          alpha, one_m, alpha64);
    fb1  <<<BATCH / 4,   64, 0, stream>>>(data, w1, s1t, bm1, flag1, alpha, one_m);
    scan2<<<BATCH / 2,   64, 0, stream>>>(s1t, w2, s2t, bm1, bm2, flag1, flag2,
                                          alpha, one_m);
    scan3<<<BATCH / 4,   64, 0, stream>>>(s2t, w3, out, bm2, flag2, alpha, one_m);
}

// Round 6
// 367.421 us; speedup vs baseline: 3.7458x; 3.6180x over previous
//
#include <hip/hip_runtime.h>
#include <stdint.h>
#include <math.h>

#define T_STEPS 4096
#define BATCH   256
#define NB_BLK  256      // T/16 spike blocks per chain

// LIF step, threshold=1:  v'=alpha*v+xs; s=max(floor(v'),0); v=v'-s
// Identity: v_new = min(v', fract(v')); s = v' - v_new (exact fp32).
// Invariant: post-step v < 1.  Zero-input step is exactly v *= alpha,
// and a no-spike step is exactly v = fma(alpha, v, y).
__device__ __forceinline__ float lif_step(float& v, float xs, float alpha) {
    float vp = fmaf(alpha, v, xs);
    float fr = vp - floorf(vp);
    float vn = fminf(vp, fr);
    float s  = vp - vn;
    v = vn;
    return s;
}

__device__ __forceinline__ float ubf(uint32_t w, int k) {
    return (float)((w >> (k * 8)) & 0xffu);
}

// ---------------------------------------------------------------------------
// seg1: one 1024-thread block per batch b = (co 0..15) x (seg 0..63).
//  (a) zeroes PRIVATE slices of out / bm1 / bm2 (no cross-block race)
//  (b) per-thread 64-step LINEAR segment response: acc_j (bit-matches the
//      serial no-spike chain), M0 = max_j acc_j, M1 = max_j(acc_j+alpha^(j+1)),
//      acc_end.
//  (c) 16 threads compose boundary values vs <- fma(alpha64, vs, acc_end) and
//      certify each segment via convexity: f(vs) <= (1-vs+)*M0 + vs+*M1,
//      vs+ = clamp(vs+1e-3,0,1).  All segments pass => channel spike-free
//      exactly.  Channel-level bad byte -> badch, batch-level OR -> flag1.
// ---------------------------------------------------------------------------
__global__ __launch_bounds__(1024) void seg1(
    const float* __restrict__ x, const float* __restrict__ w1,
    float* __restrict__ out, uint8_t* __restrict__ bm1, uint8_t* __restrict__ bm2,
    uint8_t* __restrict__ flag1, uint8_t* __restrict__ flag2,
    uint8_t* __restrict__ badch,
    float alpha, float one_m, float alpha64)
{
    const int tid = threadIdx.x;
    const int b   = blockIdx.x;

    __shared__ float sh_end[64][16];
    __shared__ float sh_m0[64][16];
    __shared__ float sh_m1[64][16];
    __shared__ int   sh_flag;

    // ---- zero per-batch slices --------------------------------------------
    float4* o4 = (float4*)(out + (size_t)b * T_STEPS * 10);   // 10240 float4
    float4 z4 = make_float4(0.f, 0.f, 0.f, 0.f);
#pragma unroll
    for (int i = 0; i < 10; ++i) o4[i * 1024 + tid] = z4;     // exactly 10240
    if (tid < 16)
        ((uint4*)(bm1 + (size_t)b * NB_BLK))[tid] = make_uint4(0u,0u,0u,0u);
    else if (tid < 32)
        ((uint4*)(bm2 + (size_t)b * NB_BLK))[tid - 16] = make_uint4(0u,0u,0u,0u);
    else if (tid == 32) { flag2[b] = 0; sh_flag = 0; }

    // ---- per-segment linear response + maxima -----------------------------
    const int co  = tid & 15;      // wave = 16 co x 4 segments -> broadcast rows
    const int seg = tid >> 4;      // 0..63

    float wr[16];
#pragma unroll
    for (int i = 0; i < 16; ++i) wr[i] = one_m * w1[co * 16 + i];

    const float4* xp = (const float4*)(x + ((size_t)b * T_STEPS + (size_t)seg * 64) * 16);

    float acc = 0.0f, m0 = -1e30f, m1 = -1e30f, pw = alpha;
    float4 c0 = xp[0], c1 = xp[1], c2 = xp[2], c3 = xp[3];
    for (int j = 0; j < 64; ++j) {
        float4 d0 = c0, d1 = c1, d2 = c2, d3 = c3;
        int jn = (j < 63) ? j + 1 : 63;
        c0 = xp[jn * 4 + 0]; c1 = xp[jn * 4 + 1];
        c2 = xp[jn * 4 + 2]; c3 = xp[jn * 4 + 3];

        float p0 = fmaf(wr[1], d0.y, wr[0] * d0.x);
        p0 = fmaf(wr[2], d0.z, p0);  p0 = fmaf(wr[3], d0.w, p0);
        float p1 = fmaf(wr[5], d1.y, wr[4] * d1.x);
        p1 = fmaf(wr[6], d1.z, p1);  p1 = fmaf(wr[7], d1.w, p1);
        float p2 = fmaf(wr[9], d2.y, wr[8] * d2.x);
        p2 = fmaf(wr[10], d2.z, p2); p2 = fmaf(wr[11], d2.w, p2);
        float p3 = fmaf(wr[13], d3.y, wr[12] * d3.x);
        p3 = fmaf(wr[14], d3.z, p3); p3 = fmaf(wr[15], d3.w, p3);
        float y = (p0 + p1) + (p2 + p3);

        acc = fmaf(alpha, acc, y);         // zero-start response acc_j
        m0  = fmaxf(m0, acc);
        m1  = fmaxf(m1, acc + pw);         // + alpha^(j+1) * 1
        pw *= alpha;
    }
    sh_end[seg][co] = acc;
    sh_m0[seg][co]  = m0;
    sh_m1[seg][co]  = m1;
    __syncthreads();

    // ---- serial composition + per-channel certification -------------------
    if (tid < 16) {
        const int c = tid;
        float vs = 0.0f;
        int bad = 0;
        for (int s = 0; s < 64; ++s) {
            float vsu = fminf(fmaxf(vs + 1e-3f, 0.0f), 1.0f);
            float bound = fmaf(1.0f - vsu, sh_m0[s][c], vsu * sh_m1[s][c]);
            bad |= (bound >= 0.999f);
            vs = fmaf(alpha64, vs, sh_end[s][c]);
        }
        badch[b * 16 + c] = (uint8_t)bad;
        if (bad) atomicOr(&sh_flag, 1);
    }
    __syncthreads();
    if (tid == 0) flag1[b] = (uint8_t)sh_flag;
}

// ---------------------------------------------------------------------------
// fbrepair: exact fallback for flagged batches. One 256-thread block per
// batch; non-flagged blocks exit immediately.
//   - zeroes s1t[b] (16 x 4096 bytes)
//   - 2 halves of 2048 steps:  (gemm into LDS, all 256 threads)  then
//     (serial LIF, threads tid<16, only channels with badch set; reads y
//     from LDS in 16-float register blocks; writes spike bytes + bm1).
// Arithmetic: gemm dot = identical fma sequence to the validated fb1 path;
// serial chain = lif_step over all 4096 steps => bit-exact spikes.
// ---------------------------------------------------------------------------
__global__ __launch_bounds__(256) void fbrepair(
    const float* __restrict__ x, const float* __restrict__ w1,
    uint8_t* __restrict__ s1t, uint8_t* __restrict__ bm1,
    const uint8_t* __restrict__ flag1, const uint8_t* __restrict__ badch,
    float alpha, float one_m)
{
    const int b = blockIdx.x;
    if (!flag1[b]) return;
    const int tid = threadIdx.x;

    __shared__ float ylds[16][2048 + 4];   // +4 pad: serial b128 reads -> 2-way

    // zero s1t[b]: 16*4096 B = 4096 uint4
    uint4* sz = (uint4*)(s1t + (size_t)b * 16 * T_STEPS);
    for (int i = tid; i < 4096; i += 256) sz[i] = make_uint4(0u,0u,0u,0u);

    const int gco = tid >> 4;              // gemm channel 0..15
    const int gtc = tid & 15;              // gemm t-chunk 0..15 (128 t each)
    float wr[16];
#pragma unroll
    for (int i = 0; i < 16; ++i) wr[i] = one_m * w1[gco * 16 + i];

    const bool serial_on = (tid < 16) && (badch[b * 16 + tid] != 0);
    float v = 0.0f;

    for (int half = 0; half < 2; ++half) {
        // ---- gemm phase: y for 2048 steps into LDS ------------------------
        const float4* xp = (const float4*)(
            x + ((size_t)b * T_STEPS + half * 2048 + gtc * 128) * 16);
        float* yrow = &ylds[gco][gtc * 128];
        for (int j = 0; j < 128; ++j) {
            float4 c0 = xp[j*4+0], c1 = xp[j*4+1], c2 = xp[j*4+2], c3 = xp[j*4+3];
            float p0 = fmaf(wr[1], c0.y, wr[0] * c0.x);
            p0 = fmaf(wr[2], c0.z, p0);  p0 = fmaf(wr[3], c0.w, p0);
            float p1 = fmaf(wr[5], c1.y, wr[4] * c1.x);
            p1 = fmaf(wr[6], c1.z, p1);  p1 = fmaf(wr[7], c1.w, p1);
            float p2 = fmaf(wr[9], c2.y, wr[8] * c2.x);
            p2 = fmaf(wr[10], c2.z, p2); p2 = fmaf(wr[11], c2.w, p2);
            float p3 = fmaf(wr[13], c3.y, wr[12] * c3.x);
            p3 = fmaf(wr[14], c3.z, p3); p3 = fmaf(wr[15], c3.w, p3);
            yrow[j] = (p0 + p1) + (p2 + p3);
        }
        __syncthreads();

        // ---- serial phase: 16 threads, bad channels only ------------------
        if (serial_on) {
            const int c = tid;
            const float4* yr = (const float4*)&ylds[c][0];   // row 16B-aligned
            uint4* op = (uint4*)(s1t + ((size_t)b * 16 + c) * T_STEPS
                                 + half * 2048);
            uint8_t* bmp = bm1 + (size_t)b * NB_BLK + half * 128;

            float4 A0 = yr[0], A1 = yr[1], A2 = yr[2], A3 = yr[3];
            for (int tb = 0; tb < 128; ++tb) {
                float4 d0 = A0, d1 = A1, d2 = A2, d3 = A3;
                int tn = (tb < 127) ? tb + 1 : 127;
                A0 = yr[tn*4+0]; A1 = yr[tn*4+1];
                A2 = yr[tn*4+2]; A3 = yr[tn*4+3];

                float cf[16];
                cf[0]=d0.x; cf[1]=d0.y; cf[2]=d0.z; cf[3]=d0.w;
                cf[4]=d1.x; cf[5]=d1.y; cf[6]=d1.z; cf[7]=d1.w;
                cf[8]=d2.x; cf[9]=d2.y; cf[10]=d2.z; cf[11]=d2.w;
                cf[12]=d3.x; cf[13]=d3.y; cf[14]=d3.z; cf[15]=d3.w;

                uint32_t w[4] = {0u,0u,0u,0u};
#pragma unroll
                for (int j = 0; j < 16; ++j) {
                    float s = lif_step(v, cf[j], alpha);
                    w[j >> 2] |= ((uint32_t)(int)s) << ((j & 3) * 8);
                }
                if (w[0] | w[1] | w[2] | w[3]) {
                    op[tb] = make_uint4(w[0], w[1], w[2], w[3]);
                    bmp[tb] = 1;
                }
            }
        }
        __syncthreads();
    }
}

// ---------------- layer-2: sparse scan, s1t -> s2t + bitmap2 ----------------
__global__ __launch_bounds__(64) void scan2(const uint8_t* __restrict__ s1t,
        const float* __restrict__ w2, uint8_t* __restrict__ s2t,
        const uint8_t* __restrict__ bm1, uint8_t* __restrict__ bm2,
        const uint8_t* __restrict__ flag1, uint8_t* __restrict__ flag2,
        float alpha, float one_m)
{
    const int tid = threadIdx.x;
    const int co  = tid & 31;
    const int b   = blockIdx.x * 2 + (tid >> 5);
    if (!flag1[b]) return;   // no layer-1 spikes in this batch -> all zero

    float wr[16];
#pragma unroll
    for (int i = 0; i < 16; ++i) wr[i] = one_m * w2[co * 16 + i];

    const uint8_t* sbase = s1t + (size_t)b * 16 * T_STEPS;
    uint4* op = (uint4*)(s2t + ((size_t)b * 32 + co) * T_STEPS);
    const uint4* bmv = (const uint4*)(bm1 + (size_t)b * NB_BLK);
    uint8_t* bm2p = bm2 + (size_t)b * NB_BLK;

    float v = 0.0f;
    for (int sb = 0; sb < 16; ++sb) {
        uint4 bm = bmv[sb];
        if ((bm.x | bm.y | bm.z | bm.w) == 0u) {
            if (v != 0.0f) {
                for (int blk = 0; blk < 16 && v != 0.0f; ++blk) {
#pragma unroll
                    for (int j = 0; j < 16; ++j) v *= alpha;
                }
            }
            continue;
        }
        for (int blk = 0; blk < 16; ++blk) {
            uint32_t d = (blk < 4) ? bm.x : (blk < 8) ? bm.y
                       : (blk < 12) ? bm.z : bm.w;
            uint32_t byte = (d >> ((blk & 3) * 8)) & 0xffu;
            if (byte == 0u) {
                if (v != 0.0f) {
#pragma unroll
                    for (int j = 0; j < 16; ++j) v *= alpha;
                }
                continue;
            }
            const int tb = sb * 16 + blk;
            const int t0 = tb * 16;
            uint4 S[16];
#pragma unroll
            for (int c = 0; c < 16; ++c)
                S[c] = *(const uint4*)(sbase + (size_t)c * T_STEPS + t0);
            uint32_t w[4] = {0u, 0u, 0u, 0u};
#pragma unroll
            for (int j = 0; j < 16; ++j) {
                float xv[16];
#pragma unroll
                for (int c = 0; c < 16; ++c) {
                    uint32_t dd = (j < 4) ? S[c].x : (j < 8) ? S[c].y
                                : (j < 12) ? S[c].z : S[c].w;
                    xv[c] = ubf(dd, j & 3);
                }
                float p0 = fmaf(wr[1], xv[1], wr[0] * xv[0]);
                p0 = fmaf(wr[2], xv[2], p0);   p0 = fmaf(wr[3], xv[3], p0);
                float p1 = fmaf(wr[5], xv[5], wr[4] * xv[4]);
                p1 = fmaf(wr[6], xv[6], p1);   p1 = fmaf(wr[7], xv[7], p1);
                float p2 = fmaf(wr[9], xv[9], wr[8] * xv[8]);
                p2 = fmaf(wr[10], xv[10], p2); p2 = fmaf(wr[11], xv[11], p2);
                float p3 = fmaf(wr[13], xv[13], wr[12] * xv[12]);
                p3 = fmaf(wr[14], xv[14], p3); p3 = fmaf(wr[15], xv[15], p3);
                float xs = (p0 + p1) + (p2 + p3);
                float s = lif_step(v, xs, alpha);
                w[j >> 2] |= ((uint32_t)(int)s) << ((j & 3) * 8);
            }
            op[tb] = make_uint4(w[0], w[1], w[2], w[3]);
            if (w[0] | w[1] | w[2] | w[3]) { bm2p[tb] = 1; flag2[b] = 1; }
        }
    }
}

// ---------------- layer-3: sparse scan, s2t -> out[b,t,10] (pre-zeroed) -----
__global__ __launch_bounds__(64) void scan3(const uint8_t* __restrict__ s2t,
        const float* __restrict__ w3, float* __restrict__ out,
        const uint8_t* __restrict__ bm2, const uint8_t* __restrict__ flag2,
        float alpha, float one_m)
{
    const int tid = threadIdx.x;
    const int co  = tid & 15;           // 10 active
    const int b   = blockIdx.x * 4 + (tid >> 4);
    if (!flag2[b]) return;   // no layer-2 spikes in this batch -> out stays 0
    const bool active = (co < 10);

    float wr[32];
#pragma unroll
    for (int i = 0; i < 32; ++i) wr[i] = active ? (one_m * w3[co * 32 + i]) : 0.0f;

    const uint8_t* sbase = s2t + (size_t)b * 32 * T_STEPS;
    const uint4* bmv = (const uint4*)(bm2 + (size_t)b * NB_BLK);
    float* ob = out + (size_t)b * T_STEPS * 10 + co;

    float v = 0.0f;
    for (int sb = 0; sb < 16; ++sb) {
        uint4 bm = bmv[sb];
        if ((bm.x | bm.y | bm.z | bm.w) == 0u) {
            if (v != 0.0f) {
                for (int blk = 0; blk < 16 && v != 0.0f; ++blk) {
#pragma unroll
                    for (int j = 0; j < 16; ++j) v *= alpha;
                }
            }
            continue;
        }
        for (int blk = 0; blk < 16; ++blk) {
            uint32_t d = (blk < 4) ? bm.x : (blk < 8) ? bm.y
                       : (blk < 12) ? bm.z : bm.w;
            uint32_t byte = (d >> ((blk & 3) * 8)) & 0xffu;
            if (byte == 0u) {
                if (v != 0.0f) {
#pragma unroll
                    for (int j = 0; j < 16; ++j) v *= alpha;
                }
                continue;
            }
            const int t0 = (sb * 16 + blk) * 16;
            uint4 S[32];
#pragma unroll
            for (int c = 0; c < 32; ++c)
                S[c] = *(const uint4*)(sbase + (size_t)c * T_STEPS + t0);
#pragma unroll
            for (int j = 0; j < 16; ++j) {
                float xv[32];
#pragma unroll
                for (int c = 0; c < 32; ++c) {
                    uint32_t dd = (j < 4) ? S[c].x : (j < 8) ? S[c].y
                                : (j < 12) ? S[c].z : S[c].w;
                    xv[c] = ubf(dd, j & 3);
                }
                float p0 = fmaf(wr[1], xv[1], wr[0] * xv[0]);
                p0 = fmaf(wr[2],  xv[2],  p0); p0 = fmaf(wr[3],  xv[3],  p0);
                p0 = fmaf(wr[4],  xv[4],  p0); p0 = fmaf(wr[5],  xv[5],  p0);
                p0 = fmaf(wr[6],  xv[6],  p0); p0 = fmaf(wr[7],  xv[7],  p0);
                float p1 = fmaf(wr[9], xv[9], wr[8] * xv[8]);
                p1 = fmaf(wr[10], xv[10], p1); p1 = fmaf(wr[11], xv[11], p1);
                p1 = fmaf(wr[12], xv[12], p1); p1 = fmaf(wr[13], xv[13], p1);
                p1 = fmaf(wr[14], xv[14], p1); p1 = fmaf(wr[15], xv[15], p1);
                float p2 = fmaf(wr[17], xv[17], wr[16] * xv[16]);
                p2 = fmaf(wr[18], xv[18], p2); p2 = fmaf(wr[19], xv[19], p2);
                p2 = fmaf(wr[20], xv[20], p2); p2 = fmaf(wr[21], xv[21], p2);
                p2 = fmaf(wr[22], xv[22], p2); p2 = fmaf(wr[23], xv[23], p2);
                float p3 = fmaf(wr[25], xv[25], wr[24] * xv[24]);
                p3 = fmaf(wr[26], xv[26], p3); p3 = fmaf(wr[27], xv[27], p3);
                p3 = fmaf(wr[28], xv[28], p3); p3 = fmaf(wr[29], xv[29], p3);
                p3 = fmaf(wr[30], xv[30], p3); p3 = fmaf(wr[31], xv[31], p3);
                float xs = (p0 + p1) + (p2 + p3);
                float s = lif_step(v, xs, alpha);
                if (active && s != 0.0f) ob[(size_t)(t0 + j) * 10] = s;
            }
        }
    }
}

extern "C" void kernel_launch(void* const* d_in, const int* in_sizes, int n_in,
                              void* d_out, int out_size, void* d_ws, size_t ws_size,
                              hipStream_t stream)
{
    const float* data = (const float*)d_in[0];
    const float* w1   = (const float*)d_in[1];
    const float* w2   = (const float*)d_in[2];
    const float* w3   = (const float*)d_in[3];
    float* out = (float*)d_out;

    // ws layout (48 MiB + 128 KiB + ~4.5 KiB):
    //   [0, 16M)    s1t  u8 [256][16][4096]
    //   [16M, 48M)  s2t  u8 [256][32][4096]
    //   [48M, ..)   bm1 64K | bm2 64K | flag1 256 | flag2 256 | badch 4K
    uint8_t* ws    = (uint8_t*)d_ws;
    uint8_t* s1t   = ws;
    uint8_t* s2t   = ws + (16u << 20);
    uint8_t* bm1   = ws + (48u << 20);
    uint8_t* bm2   = bm1 + (64u << 10);
    uint8_t* flag1 = bm2 + (64u << 10);
    uint8_t* flag2 = flag1 + 256;
    uint8_t* badch = flag2 + 256;

    const float alpha   = expf(-1.0f / 20.0f);
    const float one_m   = 1.0f - alpha;
    const float alpha64 = expf(-64.0f / 20.0f);

    seg1    <<<BATCH,   1024, 0, stream>>>(data, w1, out, bm1, bm2, flag1, flag2,
                                           badch, alpha, one_m, alpha64);
    fbrepair<<<BATCH,    256, 0, stream>>>(data, w1, s1t, bm1, flag1, badch,
                                           alpha, one_m);
    scan2   <<<BATCH/2,   64, 0, stream>>>(s1t, w2, s2t, bm1, bm2, flag1, flag2,
                                           alpha, one_m);
    scan3   <<<BATCH/4,   64, 0, stream>>>(s2t, w3, out, bm2, flag2, alpha, one_m);
}

// Round 8
// 252.651 us; speedup vs baseline: 5.4474x; 1.4543x over previous
//
#include <hip/hip_runtime.h>
#include <stdint.h>
#include <math.h>

#define T_STEPS 4096
#define BATCH   256
#define NB_BLK  256      // T/16 spike blocks per chain

// LIF step, threshold=1:  v'=alpha*v+xs; s=max(floor(v'),0); v=v'-s
// Identity: v_new = min(v', fract(v')); s = v' - v_new (exact fp32).
// No-spike step (0<=v'<1 or v'<0) is EXACTLY v = fma(alpha, v, xs).
__device__ __forceinline__ float lif_step(float& v, float xs, float alpha) {
    float vp = fmaf(alpha, v, xs);
    float fr = vp - floorf(vp);
    float vn = fminf(vp, fr);
    float s  = vp - vn;
    v = vn;
    return s;
}

__device__ __forceinline__ float ubf(uint32_t w, int k) {
    return (float)((w >> (k * 8)) & 0xffu);
}

__device__ __forceinline__ float dot16(const float wr[16],
    float4 c0, float4 c1, float4 c2, float4 c3)
{
    float p0 = fmaf(wr[1], c0.y, wr[0] * c0.x);
    p0 = fmaf(wr[2], c0.z, p0);  p0 = fmaf(wr[3], c0.w, p0);
    float p1 = fmaf(wr[5], c1.y, wr[4] * c1.x);
    p1 = fmaf(wr[6], c1.z, p1);  p1 = fmaf(wr[7], c1.w, p1);
    float p2 = fmaf(wr[9], c2.y, wr[8] * c2.x);
    p2 = fmaf(wr[10], c2.z, p2); p2 = fmaf(wr[11], c2.w, p2);
    float p3 = fmaf(wr[13], c3.y, wr[12] * c3.x);
    p3 = fmaf(wr[14], c3.z, p3); p3 = fmaf(wr[15], c3.w, p3);
    return (p0 + p1) + (p2 + p3);
}

// ---------------------------------------------------------------------------
// seg1: one 1024-thread block per batch b = (co 0..15) x (seg 0..63).
//  (a) zero PRIVATE slices of out / bm1 / bm2 / flag2
//  (b) per-thread 64-step LINEAR segment response (bit-matches the serial
//      no-spike fma chain): M0=max acc_j, M1=max(acc_j+alpha^(j+1)), acc_end.
//  (c) 16 threads compose boundary values vs <- fma(alpha64, vs, acc_end) and
//      certify per segment via convexity: f(vs) <= (1-vs+)*M0 + vs+*M1,
//      vs+ = clamp(vs+1e-3,0,1).  All-pass => channel spike-free exactly.
//  (d) For cert-bad channels (rare): zero s1t[b] (so scan2 never reads
//      unwritten bytes), recompute that channel's y[4096] in parallel into
//      LDS, then ONE thread runs the EXACT full serial LIF chain over all
//      4096 steps (R5/R6-validated semantics), writing spike blocks + bm1.
//      flag1[b] = actual spikes occurred.
// ---------------------------------------------------------------------------
__global__ __launch_bounds__(1024) void seg1(
    const float* __restrict__ x, const float* __restrict__ w1,
    float* __restrict__ out, uint8_t* __restrict__ s1t,
    uint8_t* __restrict__ bm1, uint8_t* __restrict__ bm2,
    uint8_t* __restrict__ flag1, uint8_t* __restrict__ flag2,
    float alpha, float one_m, float alpha64)
{
    const int tid = threadIdx.x;
    const int b   = blockIdx.x;

    __shared__ float   sh_end[64][16];
    __shared__ float   sh_m0[64][16];
    __shared__ float   sh_m1[64][16];
    __shared__ int     sh_badch;
    __shared__ int     sh_spike;
    __shared__ __align__(16) float ybuf[4096];

    // ---- zero per-batch slices --------------------------------------------
    float4* o4 = (float4*)(out + (size_t)b * T_STEPS * 10);   // 10240 float4
    float4 z4 = make_float4(0.f, 0.f, 0.f, 0.f);
#pragma unroll
    for (int i = 0; i < 10; ++i) o4[i * 1024 + tid] = z4;
    if (tid < 16)
        ((uint4*)(bm1 + (size_t)b * NB_BLK))[tid] = make_uint4(0u,0u,0u,0u);
    else if (tid < 32)
        ((uint4*)(bm2 + (size_t)b * NB_BLK))[tid - 16] = make_uint4(0u,0u,0u,0u);
    else if (tid == 32) { flag2[b] = 0; sh_badch = 0; sh_spike = 0; }

    // ---- per-segment linear response + maxima -----------------------------
    const int co  = tid & 15;
    const int seg = tid >> 4;

    float wr[16];
#pragma unroll
    for (int i = 0; i < 16; ++i) wr[i] = one_m * w1[co * 16 + i];

    const float4* xp = (const float4*)(x + ((size_t)b * T_STEPS + (size_t)seg * 64) * 16);

    float acc = 0.0f, m0 = -1e30f, m1 = -1e30f, pw = alpha;
    float4 A0 = xp[0], A1 = xp[1], A2 = xp[2], A3 = xp[3];
    float4 B0 = xp[4], B1 = xp[5], B2 = xp[6], B3 = xp[7];
    for (int j = 0; j < 64; ++j) {
        float4 c0 = A0, c1 = A1, c2 = A2, c3 = A3;
        A0 = B0; A1 = B1; A2 = B2; A3 = B3;
        int jn = (j + 2 < 64) ? j + 2 : 63;
        B0 = xp[jn*4+0]; B1 = xp[jn*4+1]; B2 = xp[jn*4+2]; B3 = xp[jn*4+3];

        float y = dot16(wr, c0, c1, c2, c3);
        acc = fmaf(alpha, acc, y);
        m0  = fmaxf(m0, acc);
        m1  = fmaxf(m1, acc + pw);
        pw *= alpha;
    }
    sh_end[seg][co] = acc;
    sh_m0[seg][co]  = m0;
    sh_m1[seg][co]  = m1;
    __syncthreads();

    // ---- serial composition + per-channel certification -------------------
    if (tid < 16) {
        const int c = tid;
        float vs = 0.0f;
        int bad = 0;
        for (int s = 0; s < 64; ++s) {
            float vsu = fminf(fmaxf(vs + 1e-3f, 0.0f), 1.0f);
            float bound = fmaf(1.0f - vsu, sh_m0[s][c], vsu * sh_m1[s][c]);
            bad |= (bound >= 0.999f);
            vs = fmaf(alpha64, vs, sh_end[s][c]);
        }
        if (bad) atomicOr(&sh_badch, 1 << c);
    }
    __syncthreads();

    // ---- exact repair for cert-bad channels (rare) ------------------------
    int badmask = sh_badch;
    if (badmask) {
        // dense-zero s1t[b] so scan2 never reads unwritten bytes (R7 bug fix)
        uint4* sz = (uint4*)(s1t + (size_t)b * 16 * T_STEPS);
#pragma unroll
        for (int i = 0; i < 4; ++i) sz[i * 1024 + tid] = make_uint4(0u,0u,0u,0u);
    }
    while (badmask) {
        const int c = __ffs(badmask) - 1;
        badmask &= badmask - 1;

        // recompute y[b][c][0..4095]: 4 consecutive rows per thread
        {
            float wc[16];
#pragma unroll
            for (int i = 0; i < 16; ++i) wc[i] = one_m * w1[c * 16 + i];
            const float4* xq = (const float4*)(x + ((size_t)b * T_STEPS + tid * 4) * 16);
#pragma unroll
            for (int k = 0; k < 4; ++k) {
                float4 c0 = xq[k*4+0], c1 = xq[k*4+1];
                float4 c2 = xq[k*4+2], c3 = xq[k*4+3];
                ybuf[tid * 4 + k] = dot16(wc, c0, c1, c2, c3);
            }
        }
        __syncthreads();   // ybuf ready; also orders s1t zero before writes

        if (tid == 0) {
            // full exact serial chain, all 4096 steps (R5/R6-validated)
            float v = 0.0f;
            int any = 0;
            uint8_t* op  = s1t + ((size_t)b * 16 + c) * T_STEPS;
            uint8_t* bmp = bm1 + (size_t)b * NB_BLK;
            for (int tb = 0; tb < 256; ++tb) {
                const float* yb = &ybuf[tb * 16];
                uint32_t w[4] = {0u,0u,0u,0u};
#pragma unroll
                for (int j = 0; j < 16; ++j) {
                    float sp = lif_step(v, yb[j], alpha);
                    w[j >> 2] |= ((uint32_t)(int)sp) << ((j & 3) * 8);
                }
                if (w[0] | w[1] | w[2] | w[3]) {
                    *(uint4*)(op + tb * 16) = make_uint4(w[0], w[1], w[2], w[3]);
                    bmp[tb] = 1;
                    any = 1;
                }
            }
            if (any) sh_spike = 1;
        }
        __syncthreads();
    }
    if (tid == 0) flag1[b] = (uint8_t)sh_spike;
}

// ---------------- layer-2: sparse scan, s1t -> s2t + bitmap2 ----------------
__global__ __launch_bounds__(64) void scan2(const uint8_t* __restrict__ s1t,
        const float* __restrict__ w2, uint8_t* __restrict__ s2t,
        const uint8_t* __restrict__ bm1, uint8_t* __restrict__ bm2,
        const uint8_t* __restrict__ flag1, uint8_t* __restrict__ flag2,
        float alpha, float one_m)
{
    const int tid = threadIdx.x;
    const int co  = tid & 31;
    const int b   = blockIdx.x * 2 + (tid >> 5);
    if (!flag1[b]) return;   // no layer-1 spikes in this batch -> all zero

    float wr[16];
#pragma unroll
    for (int i = 0; i < 16; ++i) wr[i] = one_m * w2[co * 16 + i];

    const uint8_t* sbase = s1t + (size_t)b * 16 * T_STEPS;
    uint4* op = (uint4*)(s2t + ((size_t)b * 32 + co) * T_STEPS);
    const uint4* bmv = (const uint4*)(bm1 + (size_t)b * NB_BLK);
    uint8_t* bm2p = bm2 + (size_t)b * NB_BLK;

    float v = 0.0f;
    for (int sb = 0; sb < 16; ++sb) {
        uint4 bm = bmv[sb];
        if ((bm.x | bm.y | bm.z | bm.w) == 0u) {
            if (v != 0.0f) {
                for (int blk = 0; blk < 16 && v != 0.0f; ++blk) {
#pragma unroll
                    for (int j = 0; j < 16; ++j) v *= alpha;
                }
            }
            continue;
        }
        for (int blk = 0; blk < 16; ++blk) {
            uint32_t d = (blk < 4) ? bm.x : (blk < 8) ? bm.y
                       : (blk < 12) ? bm.z : bm.w;
            uint32_t byte = (d >> ((blk & 3) * 8)) & 0xffu;
            if (byte == 0u) {
                if (v != 0.0f) {
#pragma unroll
                    for (int j = 0; j < 16; ++j) v *= alpha;
                }
                continue;
            }
            const int tb = sb * 16 + blk;
            const int t0 = tb * 16;
            uint4 S[16];
#pragma unroll
            for (int c = 0; c < 16; ++c)
                S[c] = *(const uint4*)(sbase + (size_t)c * T_STEPS + t0);
            uint32_t w[4] = {0u, 0u, 0u, 0u};
#pragma unroll
            for (int j = 0; j < 16; ++j) {
                float xv[16];
#pragma unroll
                for (int c = 0; c < 16; ++c) {
                    uint32_t dd = (j < 4) ? S[c].x : (j < 8) ? S[c].y
                                : (j < 12) ? S[c].z : S[c].w;
                    xv[c] = ubf(dd, j & 3);
                }
                float p0 = fmaf(wr[1], xv[1], wr[0] * xv[0]);
                p0 = fmaf(wr[2], xv[2], p0);   p0 = fmaf(wr[3], xv[3], p0);
                float p1 = fmaf(wr[5], xv[5], wr[4] * xv[4]);
                p1 = fmaf(wr[6], xv[6], p1);   p1 = fmaf(wr[7], xv[7], p1);
                float p2 = fmaf(wr[9], xv[9], wr[8] * xv[8]);
                p2 = fmaf(wr[10], xv[10], p2); p2 = fmaf(wr[11], xv[11], p2);
                float p3 = fmaf(wr[13], xv[13], wr[12] * xv[12]);
                p3 = fmaf(wr[14], xv[14], p3); p3 = fmaf(wr[15], xv[15], p3);
                float xs = (p0 + p1) + (p2 + p3);
                float s = lif_step(v, xs, alpha);
                w[j >> 2] |= ((uint32_t)(int)s) << ((j & 3) * 8);
            }
            op[tb] = make_uint4(w[0], w[1], w[2], w[3]);
            if (w[0] | w[1] | w[2] | w[3]) { bm2p[tb] = 1; flag2[b] = 1; }
        }
    }
}

// ---------------- layer-3: sparse scan, s2t -> out[b,t,10] (pre-zeroed) -----
__global__ __launch_bounds__(64) void scan3(const uint8_t* __restrict__ s2t,
        const float* __restrict__ w3, float* __restrict__ out,
        const uint8_t* __restrict__ bm2, const uint8_t* __restrict__ flag2,
        float alpha, float one_m)
{
    const int tid = threadIdx.x;
    const int co  = tid & 15;           // 10 active
    const int b   = blockIdx.x * 4 + (tid >> 4);
    if (!flag2[b]) return;   // no layer-2 spikes in this batch -> out stays 0
    const bool active = (co < 10);

    float wr[32];
#pragma unroll
    for (int i = 0; i < 32; ++i) wr[i] = active ? (one_m * w3[co * 32 + i]) : 0.0f;

    const uint8_t* sbase = s2t + (size_t)b * 32 * T_STEPS;
    const uint4* bmv = (const uint4*)(bm2 + (size_t)b * NB_BLK);
    float* ob = out + (size_t)b * T_STEPS * 10 + co;

    float v = 0.0f;
    for (int sb = 0; sb < 16; ++sb) {
        uint4 bm = bmv[sb];
        if ((bm.x | bm.y | bm.z | bm.w) == 0u) {
            if (v != 0.0f) {
                for (int blk = 0; blk < 16 && v != 0.0f; ++blk) {
#pragma unroll
                    for (int j = 0; j < 16; ++j) v *= alpha;
                }
            }
            continue;
        }
        for (int blk = 0; blk < 16; ++blk) {
            uint32_t d = (blk < 4) ? bm.x : (blk < 8) ? bm.y
                       : (blk < 12) ? bm.z : bm.w;
            uint32_t byte = (d >> ((blk & 3) * 8)) & 0xffu;
            if (byte == 0u) {
                if (v != 0.0f) {
#pragma unroll
                    for (int j = 0; j < 16; ++j) v *= alpha;
                }
                continue;
            }
            const int t0 = (sb * 16 + blk) * 16;
            uint4 S[32];
#pragma unroll
            for (int c = 0; c < 32; ++c)
                S[c] = *(const uint4*)(sbase + (size_t)c * T_STEPS + t0);
#pragma unroll
            for (int j = 0; j < 16; ++j) {
                float xv[32];
#pragma unroll
                for (int c = 0; c < 32; ++c) {
                    uint32_t dd = (j < 4) ? S[c].x : (j < 8) ? S[c].y
                                : (j < 12) ? S[c].z : S[c].w;
                    xv[c] = ubf(dd, j & 3);
                }
                float p0 = fmaf(wr[1], xv[1], wr[0] * xv[0]);
                p0 = fmaf(wr[2],  xv[2],  p0); p0 = fmaf(wr[3],  xv[3],  p0);
                p0 = fmaf(wr[4],  xv[4],  p0); p0 = fmaf(wr[5],  xv[5],  p0);
                p0 = fmaf(wr[6],  xv[6],  p0); p0 = fmaf(wr[7],  xv[7],  p0);
                float p1 = fmaf(wr[9], xv[9], wr[8] * xv[8]);
                p1 = fmaf(wr[10], xv[10], p1); p1 = fmaf(wr[11], xv[11], p1);
                p1 = fmaf(wr[12], xv[12], p1); p1 = fmaf(wr[13], xv[13], p1);
                p1 = fmaf(wr[14], xv[14], p1); p1 = fmaf(wr[15], xv[15], p1);
                float p2 = fmaf(wr[17], xv[17], wr[16] * xv[16]);
                p2 = fmaf(wr[18], xv[18], p2); p2 = fmaf(wr[19], xv[19], p2);
                p2 = fmaf(wr[20], xv[20], p2); p2 = fmaf(wr[21], xv[21], p2);
                p2 = fmaf(wr[22], xv[22], p2); p2 = fmaf(wr[23], xv[23], p2);
                float p3 = fmaf(wr[25], xv[25], wr[24] * xv[24]);
                p3 = fmaf(wr[26], xv[26], p3); p3 = fmaf(wr[27], xv[27], p3);
                p3 = fmaf(wr[28], xv[28], p3); p3 = fmaf(wr[29], xv[29], p3);
                p3 = fmaf(wr[30], xv[30], p3); p3 = fmaf(wr[31], xv[31], p3);
                float xs = (p0 + p1) + (p2 + p3);
                float s = lif_step(v, xs, alpha);
                if (active && s != 0.0f) ob[(size_t)(t0 + j) * 10] = s;
            }
        }
    }
}

extern "C" void kernel_launch(void* const* d_in, const int* in_sizes, int n_in,
                              void* d_out, int out_size, void* d_ws, size_t ws_size,
                              hipStream_t stream)
{
    const float* data = (const float*)d_in[0];
    const float* w1   = (const float*)d_in[1];
    const float* w2   = (const float*)d_in[2];
    const float* w3   = (const float*)d_in[3];
    float* out = (float*)d_out;

    // ws layout (48 MiB + 128 KiB + 512 B):
    //   [0, 16M)    s1t  u8 [256][16][4096]  (dense-zeroed only for flagged b)
    //   [16M, 48M)  s2t  u8 [256][32][4096]  (sparse: only bm2-set blocks valid)
    //   [48M, ..)   bm1 64K | bm2 64K | flag1 256 | flag2 256
    uint8_t* ws    = (uint8_t*)d_ws;
    uint8_t* s1t   = ws;
    uint8_t* s2t   = ws + (16u << 20);
    uint8_t* bm1   = ws + (48u << 20);
    uint8_t* bm2   = bm1 + (64u << 10);
    uint8_t* flag1 = bm2 + (64u << 10);
    uint8_t* flag2 = flag1 + 256;

    const float alpha   = expf(-1.0f / 20.0f);
    const float one_m   = 1.0f - alpha;
    const float alpha64 = expf(-64.0f / 20.0f);

    seg1 <<<BATCH,   1024, 0, stream>>>(data, w1, out, s1t, bm1, bm2,
                                        flag1, flag2, alpha, one_m, alpha64);
    scan2<<<BATCH/2,   64, 0, stream>>>(s1t, w2, s2t, bm1, bm2, flag1, flag2,
                                        alpha, one_m);
    scan3<<<BATCH/4,   64, 0, stream>>>(s2t, w3, out, bm2, flag2, alpha, one_m);
}

// Round 9
// 243.017 us; speedup vs baseline: 5.6633x; 1.0396x over previous
//
#include <hip/hip_runtime.h>
#include <stdint.h>
#include <math.h>

#define T_STEPS 4096
#define BATCH   256
#define NB_BLK  256      // T/16 spike blocks per chain

// LIF step, threshold=1:  v'=alpha*v+xs; s=max(floor(v'),0); v=v'-s
// Identity: v_new = min(v', fract(v')); s = v' - v_new (exact fp32).
// No-spike step (0<=v'<1 or v'<0) is EXACTLY v = fma(alpha, v, xs).
__device__ __forceinline__ float lif_step(float& v, float xs, float alpha) {
    float vp = fmaf(alpha, v, xs);
    float fr = vp - floorf(vp);
    float vn = fminf(vp, fr);
    float s  = vp - vn;
    v = vn;
    return s;
}

__device__ __forceinline__ float ubf(uint32_t w, int k) {
    return (float)((w >> (k * 8)) & 0xffu);
}

__device__ __forceinline__ float dot16(const float wr[16],
    float4 c0, float4 c1, float4 c2, float4 c3)
{
    float p0 = fmaf(wr[1], c0.y, wr[0] * c0.x);
    p0 = fmaf(wr[2], c0.z, p0);  p0 = fmaf(wr[3], c0.w, p0);
    float p1 = fmaf(wr[5], c1.y, wr[4] * c1.x);
    p1 = fmaf(wr[6], c1.z, p1);  p1 = fmaf(wr[7], c1.w, p1);
    float p2 = fmaf(wr[9], c2.y, wr[8] * c2.x);
    p2 = fmaf(wr[10], c2.z, p2); p2 = fmaf(wr[11], c2.w, p2);
    float p3 = fmaf(wr[13], c3.y, wr[12] * c3.x);
    p3 = fmaf(wr[14], c3.z, p3); p3 = fmaf(wr[15], c3.w, p3);
    return (p0 + p1) + (p2 + p3);
}

// ---------------------------------------------------------------------------
// seg1: one 1024-thread block per batch b = (co 0..15) x (seg 0..63).
//  (a) zero PRIVATE slices of out / bm1 / bm2 / flag2
//  (b) per-thread 64-step LINEAR segment response with a rolling 4-row
//      register prefetch (16 loads in flight, ~4-iter slack) — bit-matches
//      the serial no-spike fma chain.  M0=max acc_j, M1=max(acc_j+a^(j+1)),
//      acc_end -> LDS.
//  (c) 16 threads compose boundary values vs <- fma(alpha64, vs, acc_end);
//      certify per segment via convexity: f(vs) <= (1-vs+)*M0 + vs+*M1,
//      vs+ = clamp(vs+1e-3,0,1).  Margin 1e-3 >> fp32 drift.  Per-segment
//      verdicts -> sh_badseg; channel OR -> sh_badch.
//  (d) For cert-bad channels (rare): dense-zero s1t[b] (so scan2 never reads
//      unwritten bytes), recompute y[4096] in parallel into LDS, then ONE
//      thread runs the exact chain: pure fma in cert-good segments (EXACT
//      identity, no spikes possible there), full lif_step + spike/bm1 writes
//      in bad segments.  flag1[b] = actual spikes occurred.
// ---------------------------------------------------------------------------
__global__ __launch_bounds__(1024) void seg1(
    const float* __restrict__ x, const float* __restrict__ w1,
    float* __restrict__ out, uint8_t* __restrict__ s1t,
    uint8_t* __restrict__ bm1, uint8_t* __restrict__ bm2,
    uint8_t* __restrict__ flag1, uint8_t* __restrict__ flag2,
    float alpha, float one_m, float alpha64)
{
    const int tid = threadIdx.x;
    const int b   = blockIdx.x;

    __shared__ float   sh_end[64][16];
    __shared__ float   sh_m0[64][16];
    __shared__ float   sh_m1[64][16];
    __shared__ uint8_t sh_badseg[16][64];
    __shared__ int     sh_badch;
    __shared__ int     sh_spike;
    __shared__ __align__(16) float ybuf[4096];

    // ---- zero per-batch slices --------------------------------------------
    float4* o4 = (float4*)(out + (size_t)b * T_STEPS * 10);   // 10240 float4
    float4 z4 = make_float4(0.f, 0.f, 0.f, 0.f);
#pragma unroll
    for (int i = 0; i < 10; ++i) o4[i * 1024 + tid] = z4;
    if (tid < 16)
        ((uint4*)(bm1 + (size_t)b * NB_BLK))[tid] = make_uint4(0u,0u,0u,0u);
    else if (tid < 32)
        ((uint4*)(bm2 + (size_t)b * NB_BLK))[tid - 16] = make_uint4(0u,0u,0u,0u);
    else if (tid == 32) { flag2[b] = 0; sh_badch = 0; sh_spike = 0; }

    // ---- per-segment linear response + maxima -----------------------------
    const int co  = tid & 15;
    const int seg = tid >> 4;

    float wr[16];
#pragma unroll
    for (int i = 0; i < 16; ++i) wr[i] = one_m * w1[co * 16 + i];

    const float4* xp = (const float4*)(x + ((size_t)b * T_STEPS + (size_t)seg * 64) * 16);

    float acc = 0.0f, m0 = -1e30f, m1 = -1e30f, pw = alpha;

    float4 R0[4], R1[4], R2[4], R3[4];
#pragma unroll
    for (int k = 0; k < 4; ++k) R0[k] = xp[0 * 4 + k];
#pragma unroll
    for (int k = 0; k < 4; ++k) R1[k] = xp[1 * 4 + k];
#pragma unroll
    for (int k = 0; k < 4; ++k) R2[k] = xp[2 * 4 + k];
#pragma unroll
    for (int k = 0; k < 4; ++k) R3[k] = xp[3 * 4 + k];

#define SEG_STEP(RB, JROW)                                              \
    {                                                                   \
        float y = dot16(wr, RB[0], RB[1], RB[2], RB[3]);                \
        int jn = ((JROW) + 4 < 64) ? (JROW) + 4 : 63;                   \
        RB[0] = xp[jn * 4 + 0]; RB[1] = xp[jn * 4 + 1];                 \
        RB[2] = xp[jn * 4 + 2]; RB[3] = xp[jn * 4 + 3];                 \
        acc = fmaf(alpha, acc, y);                                      \
        m0  = fmaxf(m0, acc);                                           \
        m1  = fmaxf(m1, acc + pw);                                      \
        pw *= alpha;                                                    \
    }

    for (int jb = 0; jb < 64; jb += 4) {
        SEG_STEP(R0, jb + 0)
        SEG_STEP(R1, jb + 1)
        SEG_STEP(R2, jb + 2)
        SEG_STEP(R3, jb + 3)
    }
#undef SEG_STEP

    sh_end[seg][co] = acc;
    sh_m0[seg][co]  = m0;
    sh_m1[seg][co]  = m1;
    __syncthreads();

    // ---- serial composition + per-channel/per-segment certification -------
    if (tid < 16) {
        const int c = tid;
        float vs = 0.0f;
        int bad = 0;
        for (int s = 0; s < 64; ++s) {
            float vsu = fminf(fmaxf(vs + 1e-3f, 0.0f), 1.0f);
            float bound = fmaf(1.0f - vsu, sh_m0[s][c], vsu * sh_m1[s][c]);
            int sb = (bound >= 0.999f) ? 1 : 0;
            sh_badseg[c][s] = (uint8_t)sb;
            bad |= sb;
            vs = fmaf(alpha64, vs, sh_end[s][c]);
        }
        if (bad) atomicOr(&sh_badch, 1 << c);
    }
    __syncthreads();

    // ---- exact repair for cert-bad channels (rare) ------------------------
    int badmask = sh_badch;
    if (badmask) {
        // dense-zero s1t[b] so scan2 never reads unwritten bytes
        uint4* sz = (uint4*)(s1t + (size_t)b * 16 * T_STEPS);
#pragma unroll
        for (int i = 0; i < 4; ++i) sz[i * 1024 + tid] = make_uint4(0u,0u,0u,0u);
    }
    while (badmask) {
        const int c = __ffs(badmask) - 1;
        badmask &= badmask - 1;

        // recompute y[b][c][0..4095]: 4 consecutive rows per thread
        {
            float wc[16];
#pragma unroll
            for (int i = 0; i < 16; ++i) wc[i] = one_m * w1[c * 16 + i];
            const float4* xq = (const float4*)(x + ((size_t)b * T_STEPS + tid * 4) * 16);
#pragma unroll
            for (int k = 0; k < 4; ++k) {
                float4 c0 = xq[k*4+0], c1 = xq[k*4+1];
                float4 c2 = xq[k*4+2], c3 = xq[k*4+3];
                ybuf[tid * 4 + k] = dot16(wc, c0, c1, c2, c3);
            }
        }
        __syncthreads();   // ybuf ready; also orders s1t zero before writes

        if (tid == 0) {
            float v = 0.0f;
            int any = 0;
            uint8_t* op  = s1t + ((size_t)b * 16 + c) * T_STEPS;
            uint8_t* bmp = bm1 + (size_t)b * NB_BLK;
            for (int s = 0; s < 64; ++s) {
                const float* yb = &ybuf[s * 64];
                if (!sh_badseg[c][s]) {
                    // cert-good: no spike possible; lif_step == pure fma here
#pragma unroll
                    for (int j = 0; j < 64; ++j) v = fmaf(alpha, v, yb[j]);
                } else {
                    for (int tb = 0; tb < 4; ++tb) {
                        const float* yc = yb + tb * 16;
                        uint32_t w[4] = {0u,0u,0u,0u};
#pragma unroll
                        for (int j = 0; j < 16; ++j) {
                            float sp = lif_step(v, yc[j], alpha);
                            w[j >> 2] |= ((uint32_t)(int)sp) << ((j & 3) * 8);
                        }
                        if (w[0] | w[1] | w[2] | w[3]) {
                            *(uint4*)(op + s * 64 + tb * 16) =
                                make_uint4(w[0], w[1], w[2], w[3]);
                            bmp[s * 4 + tb] = 1;
                            any = 1;
                        }
                    }
                }
            }
            if (any) sh_spike = 1;
        }
        __syncthreads();
    }
    if (tid == 0) flag1[b] = (uint8_t)sh_spike;
}

// ---------------- layer-2: sparse scan, s1t -> s2t + bitmap2 ----------------
__global__ __launch_bounds__(64) void scan2(const uint8_t* __restrict__ s1t,
        const float* __restrict__ w2, uint8_t* __restrict__ s2t,
        const uint8_t* __restrict__ bm1, uint8_t* __restrict__ bm2,
        const uint8_t* __restrict__ flag1, uint8_t* __restrict__ flag2,
        float alpha, float one_m)
{
    const int tid = threadIdx.x;
    const int co  = tid & 31;
    const int b   = blockIdx.x * 2 + (tid >> 5);
    if (!flag1[b]) return;   // no layer-1 spikes in this batch -> all zero

    float wr[16];
#pragma unroll
    for (int i = 0; i < 16; ++i) wr[i] = one_m * w2[co * 16 + i];

    const uint8_t* sbase = s1t + (size_t)b * 16 * T_STEPS;
    uint4* op = (uint4*)(s2t + ((size_t)b * 32 + co) * T_STEPS);
    const uint4* bmv = (const uint4*)(bm1 + (size_t)b * NB_BLK);
    uint8_t* bm2p = bm2 + (size_t)b * NB_BLK;

    float v = 0.0f;
    for (int sb = 0; sb < 16; ++sb) {
        uint4 bm = bmv[sb];
        if ((bm.x | bm.y | bm.z | bm.w) == 0u) {
            if (v != 0.0f) {
                for (int blk = 0; blk < 16 && v != 0.0f; ++blk) {
#pragma unroll
                    for (int j = 0; j < 16; ++j) v *= alpha;
                }
            }
            continue;
        }
        for (int blk = 0; blk < 16; ++blk) {
            uint32_t d = (blk < 4) ? bm.x : (blk < 8) ? bm.y
                       : (blk < 12) ? bm.z : bm.w;
            uint32_t byte = (d >> ((blk & 3) * 8)) & 0xffu;
            if (byte == 0u) {
                if (v != 0.0f) {
#pragma unroll
                    for (int j = 0; j < 16; ++j) v *= alpha;
                }
                continue;
            }
            const int tb = sb * 16 + blk;
            const int t0 = tb * 16;
            uint4 S[16];
#pragma unroll
            for (int c = 0; c < 16; ++c)
                S[c] = *(const uint4*)(sbase + (size_t)c * T_STEPS + t0);
            uint32_t w[4] = {0u, 0u, 0u, 0u};
#pragma unroll
            for (int j = 0; j < 16; ++j) {
                float xv[16];
#pragma unroll
                for (int c = 0; c < 16; ++c) {
                    uint32_t dd = (j < 4) ? S[c].x : (j < 8) ? S[c].y
                                : (j < 12) ? S[c].z : S[c].w;
                    xv[c] = ubf(dd, j & 3);
                }
                float p0 = fmaf(wr[1], xv[1], wr[0] * xv[0]);
                p0 = fmaf(wr[2], xv[2], p0);   p0 = fmaf(wr[3], xv[3], p0);
                float p1 = fmaf(wr[5], xv[5], wr[4] * xv[4]);
                p1 = fmaf(wr[6], xv[6], p1);   p1 = fmaf(wr[7], xv[7], p1);
                float p2 = fmaf(wr[9], xv[9], wr[8] * xv[8]);
                p2 = fmaf(wr[10], xv[10], p2); p2 = fmaf(wr[11], xv[11], p2);
                float p3 = fmaf(wr[13], xv[13], wr[12] * xv[12]);
                p3 = fmaf(wr[14], xv[14], p3); p3 = fmaf(wr[15], xv[15], p3);
                float xs = (p0 + p1) + (p2 + p3);
                float s = lif_step(v, xs, alpha);
                w[j >> 2] |= ((uint32_t)(int)s) << ((j & 3) * 8);
            }
            op[tb] = make_uint4(w[0], w[1], w[2], w[3]);
            if (w[0] | w[1] | w[2] | w[3]) { bm2p[tb] = 1; flag2[b] = 1; }
        }
    }
}

// ---------------- layer-3: sparse scan, s2t -> out[b,t,10] (pre-zeroed) -----
__global__ __launch_bounds__(64) void scan3(const uint8_t* __restrict__ s2t,
        const float* __restrict__ w3, float* __restrict__ out,
        const uint8_t* __restrict__ bm2, const uint8_t* __restrict__ flag2,
        float alpha, float one_m)
{
    const int tid = threadIdx.x;
    const int co  = tid & 15;           // 10 active
    const int b   = blockIdx.x * 4 + (tid >> 4);
    if (!flag2[b]) return;   // no layer-2 spikes in this batch -> out stays 0
    const bool active = (co < 10);

    float wr[32];
#pragma unroll
    for (int i = 0; i < 32; ++i) wr[i] = active ? (one_m * w3[co * 32 + i]) : 0.0f;

    const uint8_t* sbase = s2t + (size_t)b * 32 * T_STEPS;
    const uint4* bmv = (const uint4*)(bm2 + (size_t)b * NB_BLK);
    float* ob = out + (size_t)b * T_STEPS * 10 + co;

    float v = 0.0f;
    for (int sb = 0; sb < 16; ++sb) {
        uint4 bm = bmv[sb];
        if ((bm.x | bm.y | bm.z | bm.w) == 0u) {
            if (v != 0.0f) {
                for (int blk = 0; blk < 16 && v != 0.0f; ++blk) {
#pragma unroll
                    for (int j = 0; j < 16; ++j) v *= alpha;
                }
            }
            continue;
        }
        for (int blk = 0; blk < 16; ++blk) {
            uint32_t d = (blk < 4) ? bm.x : (blk < 8) ? bm.y
                       : (blk < 12) ? bm.z : bm.w;
            uint32_t byte = (d >> ((blk & 3) * 8)) & 0xffu;
            if (byte == 0u) {
                if (v != 0.0f) {
#pragma unroll
                    for (int j = 0; j < 16; ++j) v *= alpha;
                }
                continue;
            }
            const int t0 = (sb * 16 + blk) * 16;
            uint4 S[32];
#pragma unroll
            for (int c = 0; c < 32; ++c)
                S[c] = *(const uint4*)(sbase + (size_t)c * T_STEPS + t0);
#pragma unroll
            for (int j = 0; j < 16; ++j) {
                float xv[32];
#pragma unroll
                for (int c = 0; c < 32; ++c) {
                    uint32_t dd = (j < 4) ? S[c].x : (j < 8) ? S[c].y
                                : (j < 12) ? S[c].z : S[c].w;
                    xv[c] = ubf(dd, j & 3);
                }
                float p0 = fmaf(wr[1], xv[1], wr[0] * xv[0]);
                p0 = fmaf(wr[2],  xv[2],  p0); p0 = fmaf(wr[3],  xv[3],  p0);
                p0 = fmaf(wr[4],  xv[4],  p0); p0 = fmaf(wr[5],  xv[5],  p0);
                p0 = fmaf(wr[6],  xv[6],  p0); p0 = fmaf(wr[7],  xv[7],  p0);
                float p1 = fmaf(wr[9], xv[9], wr[8] * xv[8]);
                p1 = fmaf(wr[10], xv[10], p1); p1 = fmaf(wr[11], xv[11], p1);
                p1 = fmaf(wr[12], xv[12], p1); p1 = fmaf(wr[13], xv[13], p1);
                p1 = fmaf(wr[14], xv[14], p1); p1 = fmaf(wr[15], xv[15], p1);
                float p2 = fmaf(wr[17], xv[17], wr[16] * xv[16]);
                p2 = fmaf(wr[18], xv[18], p2); p2 = fmaf(wr[19], xv[19], p2);
                p2 = fmaf(wr[20], xv[20], p2); p2 = fmaf(wr[21], xv[21], p2);
                p2 = fmaf(wr[22], xv[22], p2); p2 = fmaf(wr[23], xv[23], p2);
                float p3 = fmaf(wr[25], xv[25], wr[24] * xv[24]);
                p3 = fmaf(wr[26], xv[26], p3); p3 = fmaf(wr[27], xv[27], p3);
                p3 = fmaf(wr[28], xv[28], p3); p3 = fmaf(wr[29], xv[29], p3);
                p3 = fmaf(wr[30], xv[30], p3); p3 = fmaf(wr[31], xv[31], p3);
                float xs = (p0 + p1) + (p2 + p3);
                float s = lif_step(v, xs, alpha);
                if (active && s != 0.0f) ob[(size_t)(t0 + j) * 10] = s;
            }
        }
    }
}

extern "C" void kernel_launch(void* const* d_in, const int* in_sizes, int n_in,
                              void* d_out, int out_size, void* d_ws, size_t ws_size,
                              hipStream_t stream)
{
    const float* data = (const float*)d_in[0];
    const float* w1   = (const float*)d_in[1];
    const float* w2   = (const float*)d_in[2];
    const float* w3   = (const float*)d_in[3];
    float* out = (float*)d_out;

    // ws layout (48 MiB + 128 KiB + 512 B):
    //   [0, 16M)    s1t  u8 [256][16][4096]  (dense-zeroed only for flagged b)
    //   [16M, 48M)  s2t  u8 [256][32][4096]  (sparse: only bm2-set blocks valid)
    //   [48M, ..)   bm1 64K | bm2 64K | flag1 256 | flag2 256
    uint8_t* ws    = (uint8_t*)d_ws;
    uint8_t* s1t   = ws;
    uint8_t* s2t   = ws + (16u << 20);
    uint8_t* bm1   = ws + (48u << 20);
    uint8_t* bm2   = bm1 + (64u << 10);
    uint8_t* flag1 = bm2 + (64u << 10);
    uint8_t* flag2 = flag1 + 256;

    const float alpha   = expf(-1.0f / 20.0f);
    const float one_m   = 1.0f - alpha;
    const float alpha64 = expf(-64.0f / 20.0f);

    seg1 <<<BATCH,   1024, 0, stream>>>(data, w1, out, s1t, bm1, bm2,
                                        flag1, flag2, alpha, one_m, alpha64);
    scan2<<<BATCH/2,   64, 0, stream>>>(s1t, w2, s2t, bm1, bm2, flag1, flag2,
                                        alpha, one_m);
    scan3<<<BATCH/4,   64, 0, stream>>>(s2t, w3, out, bm2, flag2, alpha, one_m);
}

// Round 10
// 240.336 us; speedup vs baseline: 5.7265x; 1.0112x over previous
//
#include <hip/hip_runtime.h>
#include <stdint.h>
#include <math.h>

#define T_STEPS 4096
#define BATCH   256
#define NB_BLK  256      // T/16 spike blocks per chain == cert segments

// LIF step, threshold=1:  v'=alpha*v+xs; s=max(floor(v'),0); v=v'-s
// Identity: v_new = min(v', fract(v')); s = v' - v_new (exact fp32).
// No-spike step (0<=v'<1 or v'<0) is EXACTLY v = fma(alpha, v, xs).
__device__ __forceinline__ float lif_step(float& v, float xs, float alpha) {
    float vp = fmaf(alpha, v, xs);
    float fr = vp - floorf(vp);
    float vn = fminf(vp, fr);
    float s  = vp - vn;
    v = vn;
    return s;
}

__device__ __forceinline__ float ubf(uint32_t w, int k) {
    return (float)((w >> (k * 8)) & 0xffu);
}

__device__ __forceinline__ float dot16(const float wr[16],
    float4 c0, float4 c1, float4 c2, float4 c3)
{
    float p0 = fmaf(wr[1], c0.y, wr[0] * c0.x);
    p0 = fmaf(wr[2], c0.z, p0);  p0 = fmaf(wr[3], c0.w, p0);
    float p1 = fmaf(wr[5], c1.y, wr[4] * c1.x);
    p1 = fmaf(wr[6], c1.z, p1);  p1 = fmaf(wr[7], c1.w, p1);
    float p2 = fmaf(wr[9], c2.y, wr[8] * c2.x);
    p2 = fmaf(wr[10], c2.z, p2); p2 = fmaf(wr[11], c2.w, p2);
    float p3 = fmaf(wr[13], c3.y, wr[12] * c3.x);
    p3 = fmaf(wr[14], c3.z, p3); p3 = fmaf(wr[15], c3.w, p3);
    return (p0 + p1) + (p2 + p3);
}

// xbuf layout: row r (0..1023) of a chunk lives at float offset
//   (r>>4)*260 + (r&15)*16        (+4-float pad per 16-row segment)
// -> segment sg base = sg*260 floats = sg*1040 B (16-B aligned); the 4
//    distinct sg addresses in a wave are 260 floats apart = bank offset 4,
//    so the 4 b128 reads hit disjoint bank quads (co lanes broadcast).
#define XOFF(r) (((r) >> 4) * 260 + ((r) & 15) * 16)

// ---------------------------------------------------------------------------
// seg1: one 1024-thread block per batch b = (co 0..15) x (sg 0..63).
//  (a) zero PRIVATE slices of out / bm1 / bm2 / flag2
//  (b) 4 chunks x 1024 rows: cooperative coalesced stage into LDS (next
//      chunk's loads prefetched in registers), then thread (co,sg) runs the
//      16-step LINEAR segment response gs=k*64+sg from LDS (bit-matches the
//      serial no-spike fma chain): M0=max acc_j, M1=max(acc_j+alpha^(j+1)),
//      acc_end -> LDS cert arrays [256][16].
//  (c) 16 threads compose vs <- fma(alpha16, vs, acc_end) over 256 segments;
//      certify via convexity: f(vs) <= (1-vs+)*M0 + vs+*M1,
//      vs+ = clamp(vs+1e-3,0,1)  (valid for vs<=0 since M1>M0; spikes only
//      lower vs).  Margin 1e-3 >> fp32 drift.  Verdicts -> sh_badseg.
//  (d) Repair cert-bad channels (rare): dense-zero s1t[b], recompute y[4096]
//      in parallel into LDS (aliasing xbuf), ONE thread runs the exact
//      chain: pure fma in cert-good segments (exact identity), full
//      lif_step + spike/bm1 writes in bad 16-step segments.
// ---------------------------------------------------------------------------
__global__ __launch_bounds__(1024, 4) void seg1(
    const float* __restrict__ x, const float* __restrict__ w1,
    float* __restrict__ out, uint8_t* __restrict__ s1t,
    uint8_t* __restrict__ bm1, uint8_t* __restrict__ bm2,
    uint8_t* __restrict__ flag1, uint8_t* __restrict__ flag2,
    float alpha, float one_m, float alpha16)
{
    const int tid = threadIdx.x;
    const int b   = blockIdx.x;

    __shared__ __align__(16) float xbuf[16640];          // 65 KiB (chunk / ybuf)
    __shared__ float   sh_end[NB_BLK][16];               // 16 KiB
    __shared__ float   sh_m0[NB_BLK][16];
    __shared__ float   sh_m1[NB_BLK][16];
    __shared__ uint8_t sh_badseg[16][NB_BLK];            // 4 KiB
    __shared__ int     sh_badch;
    __shared__ int     sh_spike;

    // ---- zero per-batch slices --------------------------------------------
    float4* o4 = (float4*)(out + (size_t)b * T_STEPS * 10);   // 10240 float4
    float4 z4 = make_float4(0.f, 0.f, 0.f, 0.f);
#pragma unroll
    for (int i = 0; i < 10; ++i) o4[i * 1024 + tid] = z4;
    if (tid < 16)
        ((uint4*)(bm1 + (size_t)b * NB_BLK))[tid] = make_uint4(0u,0u,0u,0u);
    else if (tid < 32)
        ((uint4*)(bm2 + (size_t)b * NB_BLK))[tid - 16] = make_uint4(0u,0u,0u,0u);
    else if (tid == 32) { flag2[b] = 0; sh_badch = 0; sh_spike = 0; }

    const int co = tid & 15;
    const int sg = tid >> 4;          // 0..63 segment-within-chunk

    float wr[16];
#pragma unroll
    for (int i = 0; i < 16; ++i) wr[i] = one_m * w1[co * 16 + i];

    const float4* xg = (const float4*)(x + (size_t)b * T_STEPS * 16); // 16384 f4

    // prefetch chunk 0
    float4 cur[4], nxt[4];
#pragma unroll
    for (int p = 0; p < 4; ++p) cur[p] = xg[p * 1024 + tid];

    const int sbase = sg * 260;
    for (int k = 0; k < 4; ++k) {
        __syncthreads();              // xbuf free (previous compute done)
        // store staged chunk (padded layout)
#pragma unroll
        for (int p = 0; p < 4; ++p) {
            int f = p * 1024 + tid;   // float4 index within chunk
            int r = f >> 2, c = f & 3;
            *(float4*)&xbuf[XOFF(r) + c * 4] = cur[p];
        }
        if (k < 3) {
#pragma unroll
            for (int p = 0; p < 4; ++p) nxt[p] = xg[(k + 1) * 4096 + p * 1024 + tid];
        }
        __syncthreads();              // xbuf ready

        float acc = 0.0f, m0 = -1e30f, m1 = -1e30f, pw = alpha;
#pragma unroll
        for (int j = 0; j < 16; ++j) {
            const float* rp = &xbuf[sbase + j * 16];
            float4 c0 = *(const float4*)(rp + 0);
            float4 c1 = *(const float4*)(rp + 4);
            float4 c2 = *(const float4*)(rp + 8);
            float4 c3 = *(const float4*)(rp + 12);
            float y = dot16(wr, c0, c1, c2, c3);
            acc = fmaf(alpha, acc, y);
            m0  = fmaxf(m0, acc);
            m1  = fmaxf(m1, acc + pw);
            pw *= alpha;
        }
        const int gs = k * 64 + sg;
        sh_end[gs][co] = acc;
        sh_m0[gs][co]  = m0;
        sh_m1[gs][co]  = m1;

#pragma unroll
        for (int p = 0; p < 4; ++p) cur[p] = nxt[p];
    }
    __syncthreads();

    // ---- serial composition + per-channel/per-segment certification -------
    if (tid < 16) {
        const int c = tid;
        float vs = 0.0f;
        int bad = 0;
        for (int s = 0; s < NB_BLK; ++s) {
            float vsu = fminf(fmaxf(vs + 1e-3f, 0.0f), 1.0f);
            float bound = fmaf(1.0f - vsu, sh_m0[s][c], vsu * sh_m1[s][c]);
            int sb = (bound >= 0.999f) ? 1 : 0;
            sh_badseg[c][s] = (uint8_t)sb;
            bad |= sb;
            vs = fmaf(alpha16, vs, sh_end[s][c]);
        }
        if (bad) atomicOr(&sh_badch, 1 << c);
    }
    __syncthreads();

    // ---- exact repair for cert-bad channels (rare) ------------------------
    int badmask = sh_badch;
    if (badmask) {
        // dense-zero s1t[b] so scan2 never reads unwritten bytes
        uint4* sz = (uint4*)(s1t + (size_t)b * 16 * T_STEPS);
#pragma unroll
        for (int i = 0; i < 4; ++i) sz[i * 1024 + tid] = make_uint4(0u,0u,0u,0u);
    }
    float* ybuf = xbuf;   // alias: staging done, reuse as y[4096]
    while (badmask) {
        const int c = __ffs(badmask) - 1;
        badmask &= badmask - 1;

        {   // recompute y[b][c][0..4095]: 4 consecutive rows per thread
            float wc[16];
#pragma unroll
            for (int i = 0; i < 16; ++i) wc[i] = one_m * w1[c * 16 + i];
            const float4* xq = xg + (size_t)tid * 16;   // rows tid*4..tid*4+3
#pragma unroll
            for (int kk = 0; kk < 4; ++kk) {
                float4 c0 = xq[kk*4+0], c1 = xq[kk*4+1];
                float4 c2 = xq[kk*4+2], c3 = xq[kk*4+3];
                ybuf[tid * 4 + kk] = dot16(wc, c0, c1, c2, c3);
            }
        }
        __syncthreads();   // ybuf ready; also orders s1t zero before writes

        if (tid == 0) {
            float v = 0.0f;
            int any = 0;
            uint8_t* op  = s1t + ((size_t)b * 16 + c) * T_STEPS;
            uint8_t* bmp = bm1 + (size_t)b * NB_BLK;
            for (int s = 0; s < NB_BLK; ++s) {
                const float* yb = &ybuf[s * 16];
                if (!sh_badseg[c][s]) {
                    // cert-good: no spike possible; lif_step == pure fma here
#pragma unroll
                    for (int j = 0; j < 16; ++j) v = fmaf(alpha, v, yb[j]);
                } else {
                    uint32_t w[4] = {0u,0u,0u,0u};
#pragma unroll
                    for (int j = 0; j < 16; ++j) {
                        float sp = lif_step(v, yb[j], alpha);
                        w[j >> 2] |= ((uint32_t)(int)sp) << ((j & 3) * 8);
                    }
                    if (w[0] | w[1] | w[2] | w[3]) {
                        *(uint4*)(op + s * 16) = make_uint4(w[0], w[1], w[2], w[3]);
                        bmp[s] = 1;
                        any = 1;
                    }
                }
            }
            if (any) sh_spike = 1;
        }
        __syncthreads();
    }
    if (tid == 0) flag1[b] = (uint8_t)sh_spike;
}

// ---------------- layer-2: sparse scan, s1t -> s2t + bitmap2 ----------------
__global__ __launch_bounds__(64) void scan2(const uint8_t* __restrict__ s1t,
        const float* __restrict__ w2, uint8_t* __restrict__ s2t,
        const uint8_t* __restrict__ bm1, uint8_t* __restrict__ bm2,
        const uint8_t* __restrict__ flag1, uint8_t* __restrict__ flag2,
        float alpha, float one_m)
{
    const int tid = threadIdx.x;
    const int co  = tid & 31;
    const int b   = blockIdx.x * 2 + (tid >> 5);
    if (!flag1[b]) return;   // no layer-1 spikes in this batch -> all zero

    float wr[16];
#pragma unroll
    for (int i = 0; i < 16; ++i) wr[i] = one_m * w2[co * 16 + i];

    const uint8_t* sbase = s1t + (size_t)b * 16 * T_STEPS;
    uint4* op = (uint4*)(s2t + ((size_t)b * 32 + co) * T_STEPS);
    const uint4* bmv = (const uint4*)(bm1 + (size_t)b * NB_BLK);
    uint8_t* bm2p = bm2 + (size_t)b * NB_BLK;

    float v = 0.0f;
    for (int sb = 0; sb < 16; ++sb) {
        uint4 bm = bmv[sb];
        if ((bm.x | bm.y | bm.z | bm.w) == 0u) {
            if (v != 0.0f) {
                for (int blk = 0; blk < 16 && v != 0.0f; ++blk) {
#pragma unroll
                    for (int j = 0; j < 16; ++j) v *= alpha;
                }
            }
            continue;
        }
        for (int blk = 0; blk < 16; ++blk) {
            uint32_t d = (blk < 4) ? bm.x : (blk < 8) ? bm.y
                       : (blk < 12) ? bm.z : bm.w;
            uint32_t byte = (d >> ((blk & 3) * 8)) & 0xffu;
            if (byte == 0u) {
                if (v != 0.0f) {
#pragma unroll
                    for (int j = 0; j < 16; ++j) v *= alpha;
                }
                continue;
            }
            const int tb = sb * 16 + blk;
            const int t0 = tb * 16;
            uint4 S[16];
#pragma unroll
            for (int c = 0; c < 16; ++c)
                S[c] = *(const uint4*)(sbase + (size_t)c * T_STEPS + t0);
            uint32_t w[4] = {0u, 0u, 0u, 0u};
#pragma unroll
            for (int j = 0; j < 16; ++j) {
                float xv[16];
#pragma unroll
                for (int c = 0; c < 16; ++c) {
                    uint32_t dd = (j < 4) ? S[c].x : (j < 8) ? S[c].y
                                : (j < 12) ? S[c].z : S[c].w;
                    xv[c] = ubf(dd, j & 3);
                }
                float p0 = fmaf(wr[1], xv[1], wr[0] * xv[0]);
                p0 = fmaf(wr[2], xv[2], p0);   p0 = fmaf(wr[3], xv[3], p0);
                float p1 = fmaf(wr[5], xv[5], wr[4] * xv[4]);
                p1 = fmaf(wr[6], xv[6], p1);   p1 = fmaf(wr[7], xv[7], p1);
                float p2 = fmaf(wr[9], xv[9], wr[8] * xv[8]);
                p2 = fmaf(wr[10], xv[10], p2); p2 = fmaf(wr[11], xv[11], p2);
                float p3 = fmaf(wr[13], xv[13], wr[12] * xv[12]);
                p3 = fmaf(wr[14], xv[14], p3); p3 = fmaf(wr[15], xv[15], p3);
                float xs = (p0 + p1) + (p2 + p3);
                float s = lif_step(v, xs, alpha);
                w[j >> 2] |= ((uint32_t)(int)s) << ((j & 3) * 8);
            }
            op[tb] = make_uint4(w[0], w[1], w[2], w[3]);
            if (w[0] | w[1] | w[2] | w[3]) { bm2p[tb] = 1; flag2[b] = 1; }
        }
    }
}

// ---------------- layer-3: sparse scan, s2t -> out[b,t,10] (pre-zeroed) -----
__global__ __launch_bounds__(64) void scan3(const uint8_t* __restrict__ s2t,
        const float* __restrict__ w3, float* __restrict__ out,
        const uint8_t* __restrict__ bm2, const uint8_t* __restrict__ flag2,
        float alpha, float one_m)
{
    const int tid = threadIdx.x;
    const int co  = tid & 15;           // 10 active
    const int b   = blockIdx.x * 4 + (tid >> 4);
    if (!flag2[b]) return;   // no layer-2 spikes in this batch -> out stays 0
    const bool active = (co < 10);

    float wr[32];
#pragma unroll
    for (int i = 0; i < 32; ++i) wr[i] = active ? (one_m * w3[co * 32 + i]) : 0.0f;

    const uint8_t* sbase = s2t + (size_t)b * 32 * T_STEPS;
    const uint4* bmv = (const uint4*)(bm2 + (size_t)b * NB_BLK);
    float* ob = out + (size_t)b * T_STEPS * 10 + co;

    float v = 0.0f;
    for (int sb = 0; sb < 16; ++sb) {
        uint4 bm = bmv[sb];
        if ((bm.x | bm.y | bm.z | bm.w) == 0u) {
            if (v != 0.0f) {
                for (int blk = 0; blk < 16 && v != 0.0f; ++blk) {
#pragma unroll
                    for (int j = 0; j < 16; ++j) v *= alpha;
                }
            }
            continue;
        }
        for (int blk = 0; blk < 16; ++blk) {
            uint32_t d = (blk < 4) ? bm.x : (blk < 8) ? bm.y
                       : (blk < 12) ? bm.z : bm.w;
            uint32_t byte = (d >> ((blk & 3) * 8)) & 0xffu;
            if (byte == 0u) {
                if (v != 0.0f) {
#pragma unroll
                    for (int j = 0; j < 16; ++j) v *= alpha;
                }
                continue;
            }
            const int t0 = (sb * 16 + blk) * 16;
            uint4 S[32];
#pragma unroll
            for (int c = 0; c < 32; ++c)
                S[c] = *(const uint4*)(sbase + (size_t)c * T_STEPS + t0);
#pragma unroll
            for (int j = 0; j < 16; ++j) {
                float xv[32];
#pragma unroll
                for (int c = 0; c < 32; ++c) {
                    uint32_t dd = (j < 4) ? S[c].x : (j < 8) ? S[c].y
                                : (j < 12) ? S[c].z : S[c].w;
                    xv[c] = ubf(dd, j & 3);
                }
                float p0 = fmaf(wr[1], xv[1], wr[0] * xv[0]);
                p0 = fmaf(wr[2],  xv[2],  p0); p0 = fmaf(wr[3],  xv[3],  p0);
                p0 = fmaf(wr[4],  xv[4],  p0); p0 = fmaf(wr[5],  xv[5],  p0);
                p0 = fmaf(wr[6],  xv[6],  p0); p0 = fmaf(wr[7],  xv[7],  p0);
                float p1 = fmaf(wr[9], xv[9], wr[8] * xv[8]);
                p1 = fmaf(wr[10], xv[10], p1); p1 = fmaf(wr[11], xv[11], p1);
                p1 = fmaf(wr[12], xv[12], p1); p1 = fmaf(wr[13], xv[13], p1);
                p1 = fmaf(wr[14], xv[14], p1); p1 = fmaf(wr[15], xv[15], p1);
                float p2 = fmaf(wr[17], xv[17], wr[16] * xv[16]);
                p2 = fmaf(wr[18], xv[18], p2); p2 = fmaf(wr[19], xv[19], p2);
                p2 = fmaf(wr[20], xv[20], p2); p2 = fmaf(wr[21], xv[21], p2);
                p2 = fmaf(wr[22], xv[22], p2); p2 = fmaf(wr[23], xv[23], p2);
                float p3 = fmaf(wr[25], xv[25], wr[24] * xv[24]);
                p3 = fmaf(wr[26], xv[26], p3); p3 = fmaf(wr[27], xv[27], p3);
                p3 = fmaf(wr[28], xv[28], p3); p3 = fmaf(wr[29], xv[29], p3);
                p3 = fmaf(wr[30], xv[30], p3); p3 = fmaf(wr[31], xv[31], p3);
                float xs = (p0 + p1) + (p2 + p3);
                float s = lif_step(v, xs, alpha);
                if (active && s != 0.0f) ob[(size_t)(t0 + j) * 10] = s;
            }
        }
    }
}

extern "C" void kernel_launch(void* const* d_in, const int* in_sizes, int n_in,
                              void* d_out, int out_size, void* d_ws, size_t ws_size,
                              hipStream_t stream)
{
    const float* data = (const float*)d_in[0];
    const float* w1   = (const float*)d_in[1];
    const float* w2   = (const float*)d_in[2];
    const float* w3   = (const float*)d_in[3];
    float* out = (float*)d_out;

    // ws layout (48 MiB + 128 KiB + 512 B):
    //   [0, 16M)    s1t  u8 [256][16][4096]  (dense-zeroed only for flagged b)
    //   [16M, 48M)  s2t  u8 [256][32][4096]  (sparse: only bm2-set blocks valid)
    //   [48M, ..)   bm1 64K | bm2 64K | flag1 256 | flag2 256
    uint8_t* ws    = (uint8_t*)d_ws;
    uint8_t* s1t   = ws;
    uint8_t* s2t   = ws + (16u << 20);
    uint8_t* bm1   = ws + (48u << 20);
    uint8_t* bm2   = bm1 + (64u << 10);
    uint8_t* flag1 = bm2 + (64u << 10);
    uint8_t* flag2 = flag1 + 256;

    const float alpha   = expf(-1.0f / 20.0f);
    const float one_m   = 1.0f - alpha;
    const float alpha16 = expf(-16.0f / 20.0f);

    seg1 <<<BATCH,   1024, 0, stream>>>(data, w1, out, s1t, bm1, bm2,
                                        flag1, flag2, alpha, one_m, alpha16);
    scan2<<<BATCH/2,   64, 0, stream>>>(s1t, w2, s2t, bm1, bm2, flag1, flag2,
                                        alpha, one_m);
    scan3<<<BATCH/4,   64, 0, stream>>>(s2t, w3, out, bm2, flag2, alpha, one_m);
}

// Round 11
// 224.566 us; speedup vs baseline: 6.1286x; 1.0702x over previous
//
#include <hip/hip_runtime.h>
#include <stdint.h>
#include <math.h>

#define T_STEPS 4096
#define BATCH   256
#define NB_BLK  256      // T/16 spike blocks per chain == cert segments

// LIF step, threshold=1:  v'=alpha*v+xs; s=max(floor(v'),0); v=v'-s
// Identity: v_new = min(v', fract(v')); s = v' - v_new (exact fp32).
// No-spike step (0<=v'<1 or v'<0) is EXACTLY v = fma(alpha, v, xs).
__device__ __forceinline__ float lif_step(float& v, float xs, float alpha) {
    float vp = fmaf(alpha, v, xs);
    float fr = vp - floorf(vp);
    float vn = fminf(vp, fr);
    float s  = vp - vn;
    v = vn;
    return s;
}

__device__ __forceinline__ float ubf(uint32_t w, int k) {
    return (float)((w >> (k * 8)) & 0xffu);
}

__device__ __forceinline__ float dot16(const float wr[16],
    float4 c0, float4 c1, float4 c2, float4 c3)
{
    float p0 = fmaf(wr[1], c0.y, wr[0] * c0.x);
    p0 = fmaf(wr[2], c0.z, p0);  p0 = fmaf(wr[3], c0.w, p0);
    float p1 = fmaf(wr[5], c1.y, wr[4] * c1.x);
    p1 = fmaf(wr[6], c1.z, p1);  p1 = fmaf(wr[7], c1.w, p1);
    float p2 = fmaf(wr[9], c2.y, wr[8] * c2.x);
    p2 = fmaf(wr[10], c2.z, p2); p2 = fmaf(wr[11], c2.w, p2);
    float p3 = fmaf(wr[13], c3.y, wr[12] * c3.x);
    p3 = fmaf(wr[14], c3.z, p3); p3 = fmaf(wr[15], c3.w, p3);
    return (p0 + p1) + (p2 + p3);
}

// xbuf layout: row r (0..1023) of a chunk lives at float offset
//   (r>>4)*260 + (r&15)*16        (+4-float pad per 16-row segment)
// -> the 4 distinct sg-addresses in a wave are 260 floats apart (bank
//    offset 4), so the 4 b128 reads hit disjoint bank quads (co lanes
//    broadcast) — conflict-free.
#define XOFF(r) (((r) >> 4) * 260 + ((r) & 15) * 16)

// ---------------------------------------------------------------------------
// seg1: one 1024-thread block per batch b = (co 0..15) x (sg 0..63).
//  (a) zero PRIVATE slices of out / bm1 / bm2 / flag2
//  (b) 4 chunks x 1024 rows: cooperative coalesced stage into LDS
//      (NO register double-buffer — R9/R10 showed it spills to scratch and
//      adds ~130 MB of HBM traffic), then thread (co,sg) runs the 16-step
//      LINEAR segment response gs=k*64+sg from LDS (bit-matches the serial
//      no-spike fma chain): M0=max acc_j, M1=max(acc_j+alpha^(j+1)),
//      acc_end -> LDS cert arrays [256][16].
//  (c) 16 threads compose vs <- fma(alpha16, vs, acc_end) over 256 segments;
//      certify via convexity: f(vs) <= (1-vs+)*M0 + vs+*M1,
//      vs+ = clamp(vs+1e-3,0,1)  (valid for vs<=0 since M1>M0; spikes only
//      lower vs).  Margin 1e-3 >> fp32 drift.  Verdicts -> sh_badseg.
//  (d) Repair cert-bad channels (rare): dense-zero s1t[b], recompute y[4096]
//      in parallel into LDS (aliasing xbuf), ONE thread runs the exact
//      chain: pure fma in cert-good segments (exact identity), full
//      lif_step + spike/bm1 writes in bad 16-step segments.
// ---------------------------------------------------------------------------
__global__ __launch_bounds__(1024) void seg1(
    const float* __restrict__ x, const float* __restrict__ w1,
    float* __restrict__ out, uint8_t* __restrict__ s1t,
    uint8_t* __restrict__ bm1, uint8_t* __restrict__ bm2,
    uint8_t* __restrict__ flag1, uint8_t* __restrict__ flag2,
    float alpha, float one_m, float alpha16)
{
    const int tid = threadIdx.x;
    const int b   = blockIdx.x;

    __shared__ __align__(16) float xbuf[16640];          // 65 KiB (chunk / ybuf)
    __shared__ float   sh_end[NB_BLK][16];               // 16 KiB
    __shared__ float   sh_m0[NB_BLK][16];
    __shared__ float   sh_m1[NB_BLK][16];
    __shared__ uint8_t sh_badseg[16][NB_BLK];            // 4 KiB
    __shared__ int     sh_badch;
    __shared__ int     sh_spike;

    // ---- zero per-batch slices --------------------------------------------
    float4* o4 = (float4*)(out + (size_t)b * T_STEPS * 10);   // 10240 float4
    float4 z4 = make_float4(0.f, 0.f, 0.f, 0.f);
#pragma unroll
    for (int i = 0; i < 10; ++i) o4[i * 1024 + tid] = z4;
    if (tid < 16)
        ((uint4*)(bm1 + (size_t)b * NB_BLK))[tid] = make_uint4(0u,0u,0u,0u);
    else if (tid < 32)
        ((uint4*)(bm2 + (size_t)b * NB_BLK))[tid - 16] = make_uint4(0u,0u,0u,0u);
    else if (tid == 32) { flag2[b] = 0; sh_badch = 0; sh_spike = 0; }

    const int co = tid & 15;
    const int sg = tid >> 4;          // 0..63 segment-within-chunk

    float wr[16];
#pragma unroll
    for (int i = 0; i < 16; ++i) wr[i] = one_m * w1[co * 16 + i];

    const float4* xg = (const float4*)(x + (size_t)b * T_STEPS * 16); // 16384 f4

    const int sbase = sg * 260;
    for (int k = 0; k < 4; ++k) {
        // coalesced load of this chunk (16 regs live; no prefetch array)
        float4 cur[4];
#pragma unroll
        for (int p = 0; p < 4; ++p) cur[p] = xg[k * 4096 + p * 1024 + tid];
        __syncthreads();              // xbuf free (previous compute done)
#pragma unroll
        for (int p = 0; p < 4; ++p) {
            int f = p * 1024 + tid;   // float4 index within chunk
            int r = f >> 2, c = f & 3;
            *(float4*)&xbuf[XOFF(r) + c * 4] = cur[p];
        }
        __syncthreads();              // xbuf ready

        float acc = 0.0f, m0 = -1e30f, m1 = -1e30f, pw = alpha;
#pragma unroll
        for (int j = 0; j < 16; ++j) {
            const float* rp = &xbuf[sbase + j * 16];
            float4 c0 = *(const float4*)(rp + 0);
            float4 c1 = *(const float4*)(rp + 4);
            float4 c2 = *(const float4*)(rp + 8);
            float4 c3 = *(const float4*)(rp + 12);
            float y = dot16(wr, c0, c1, c2, c3);
            acc = fmaf(alpha, acc, y);
            m0  = fmaxf(m0, acc);
            m1  = fmaxf(m1, acc + pw);
            pw *= alpha;
        }
        const int gs = k * 64 + sg;
        sh_end[gs][co] = acc;
        sh_m0[gs][co]  = m0;
        sh_m1[gs][co]  = m1;
    }
    __syncthreads();

    // ---- serial composition + per-channel/per-segment certification -------
    if (tid < 16) {
        const int c = tid;
        float vs = 0.0f;
        int bad = 0;
        for (int s = 0; s < NB_BLK; ++s) {
            float vsu = fminf(fmaxf(vs + 1e-3f, 0.0f), 1.0f);
            float bound = fmaf(1.0f - vsu, sh_m0[s][c], vsu * sh_m1[s][c]);
            int sb = (bound >= 0.999f) ? 1 : 0;
            sh_badseg[c][s] = (uint8_t)sb;
            bad |= sb;
            vs = fmaf(alpha16, vs, sh_end[s][c]);
        }
        if (bad) atomicOr(&sh_badch, 1 << c);
    }
    __syncthreads();

    // ---- exact repair for cert-bad channels (rare) ------------------------
    int badmask = sh_badch;
    if (badmask) {
        // dense-zero s1t[b] so scan2 never reads unwritten bytes
        uint4* sz = (uint4*)(s1t + (size_t)b * 16 * T_STEPS);
#pragma unroll
        for (int i = 0; i < 4; ++i) sz[i * 1024 + tid] = make_uint4(0u,0u,0u,0u);
    }
    float* ybuf = xbuf;   // alias: staging done, reuse as y[4096]
    while (badmask) {
        const int c = __ffs(badmask) - 1;
        badmask &= badmask - 1;

        {   // recompute y[b][c][0..4095]: 4 consecutive rows per thread
            float wc[16];
#pragma unroll
            for (int i = 0; i < 16; ++i) wc[i] = one_m * w1[c * 16 + i];
            const float4* xq = xg + (size_t)tid * 16;   // rows tid*4..tid*4+3
#pragma unroll
            for (int kk = 0; kk < 4; ++kk) {
                float4 c0 = xq[kk*4+0], c1 = xq[kk*4+1];
                float4 c2 = xq[kk*4+2], c3 = xq[kk*4+3];
                ybuf[tid * 4 + kk] = dot16(wc, c0, c1, c2, c3);
            }
        }
        __syncthreads();   // ybuf ready; also orders s1t zero before writes

        if (tid == 0) {
            float v = 0.0f;
            int any = 0;
            uint8_t* op  = s1t + ((size_t)b * 16 + c) * T_STEPS;
            uint8_t* bmp = bm1 + (size_t)b * NB_BLK;
            for (int s = 0; s < NB_BLK; ++s) {
                const float* yb = &ybuf[s * 16];
                if (!sh_badseg[c][s]) {
                    // cert-good: no spike possible; lif_step == pure fma here
#pragma unroll
                    for (int j = 0; j < 16; ++j) v = fmaf(alpha, v, yb[j]);
                } else {
                    uint32_t w[4] = {0u,0u,0u,0u};
#pragma unroll
                    for (int j = 0; j < 16; ++j) {
                        float sp = lif_step(v, yb[j], alpha);
                        w[j >> 2] |= ((uint32_t)(int)sp) << ((j & 3) * 8);
                    }
                    if (w[0] | w[1] | w[2] | w[3]) {
                        *(uint4*)(op + s * 16) = make_uint4(w[0], w[1], w[2], w[3]);
                        bmp[s] = 1;
                        any = 1;
                    }
                }
            }
            if (any) sh_spike = 1;
        }
        __syncthreads();
    }
    if (tid == 0) flag1[b] = (uint8_t)sh_spike;
}

// ---------------- layer-2: sparse scan, s1t -> s2t + bitmap2 ----------------
__global__ __launch_bounds__(64) void scan2(const uint8_t* __restrict__ s1t,
        const float* __restrict__ w2, uint8_t* __restrict__ s2t,
        const uint8_t* __restrict__ bm1, uint8_t* __restrict__ bm2,
        const uint8_t* __restrict__ flag1, uint8_t* __restrict__ flag2,
        float alpha, float one_m)
{
    const int tid = threadIdx.x;
    const int co  = tid & 31;
    const int b   = blockIdx.x * 2 + (tid >> 5);
    if (!flag1[b]) return;   // no layer-1 spikes in this batch -> all zero

    float wr[16];
#pragma unroll
    for (int i = 0; i < 16; ++i) wr[i] = one_m * w2[co * 16 + i];

    const uint8_t* sbase = s1t + (size_t)b * 16 * T_STEPS;
    uint4* op = (uint4*)(s2t + ((size_t)b * 32 + co) * T_STEPS);
    const uint4* bmv = (const uint4*)(bm1 + (size_t)b * NB_BLK);
    uint8_t* bm2p = bm2 + (size_t)b * NB_BLK;

    float v = 0.0f;
    for (int sb = 0; sb < 16; ++sb) {
        uint4 bm = bmv[sb];
        if ((bm.x | bm.y | bm.z | bm.w) == 0u) {
            if (v != 0.0f) {
                for (int blk = 0; blk < 16 && v != 0.0f; ++blk) {
#pragma unroll
                    for (int j = 0; j < 16; ++j) v *= alpha;
                }
            }
            continue;
        }
        for (int blk = 0; blk < 16; ++blk) {
            uint32_t d = (blk < 4) ? bm.x : (blk < 8) ? bm.y
                       : (blk < 12) ? bm.z : bm.w;
            uint32_t byte = (d >> ((blk & 3) * 8)) & 0xffu;
            if (byte == 0u) {
                if (v != 0.0f) {
#pragma unroll
                    for (int j = 0; j < 16; ++j) v *= alpha;
                }
                continue;
            }
            const int tb = sb * 16 + blk;
            const int t0 = tb * 16;
            uint4 S[16];
#pragma unroll
            for (int c = 0; c < 16; ++c)
                S[c] = *(const uint4*)(sbase + (size_t)c * T_STEPS + t0);
            uint32_t w[4] = {0u, 0u, 0u, 0u};
#pragma unroll
            for (int j = 0; j < 16; ++j) {
                float xv[16];
#pragma unroll
                for (int c = 0; c < 16; ++c) {
                    uint32_t dd = (j < 4) ? S[c].x : (j < 8) ? S[c].y
                                : (j < 12) ? S[c].z : S[c].w;
                    xv[c] = ubf(dd, j & 3);
                }
                float p0 = fmaf(wr[1], xv[1], wr[0] * xv[0]);
                p0 = fmaf(wr[2], xv[2], p0);   p0 = fmaf(wr[3], xv[3], p0);
                float p1 = fmaf(wr[5], xv[5], wr[4] * xv[4]);
                p1 = fmaf(wr[6], xv[6], p1);   p1 = fmaf(wr[7], xv[7], p1);
                float p2 = fmaf(wr[9], xv[9], wr[8] * xv[8]);
                p2 = fmaf(wr[10], xv[10], p2); p2 = fmaf(wr[11], xv[11], p2);
                float p3 = fmaf(wr[13], xv[13], wr[12] * xv[12]);
                p3 = fmaf(wr[14], xv[14], p3); p3 = fmaf(wr[15], xv[15], p3);
                float xs = (p0 + p1) + (p2 + p3);
                float s = lif_step(v, xs, alpha);
                w[j >> 2] |= ((uint32_t)(int)s) << ((j & 3) * 8);
            }
            op[tb] = make_uint4(w[0], w[1], w[2], w[3]);
            if (w[0] | w[1] | w[2] | w[3]) { bm2p[tb] = 1; flag2[b] = 1; }
        }
    }
}

// ---------------- layer-3: sparse scan, s2t -> out[b,t,10] (pre-zeroed) -----
__global__ __launch_bounds__(64) void scan3(const uint8_t* __restrict__ s2t,
        const float* __restrict__ w3, float* __restrict__ out,
        const uint8_t* __restrict__ bm2, const uint8_t* __restrict__ flag2,
        float alpha, float one_m)
{
    const int tid = threadIdx.x;
    const int co  = tid & 15;           // 10 active
    const int b   = blockIdx.x * 4 + (tid >> 4);
    if (!flag2[b]) return;   // no layer-2 spikes in this batch -> out stays 0
    const bool active = (co < 10);

    float wr[32];
#pragma unroll
    for (int i = 0; i < 32; ++i) wr[i] = active ? (one_m * w3[co * 32 + i]) : 0.0f;

    const uint8_t* sbase = s2t + (size_t)b * 32 * T_STEPS;
    const uint4* bmv = (const uint4*)(bm2 + (size_t)b * NB_BLK);
    float* ob = out + (size_t)b * T_STEPS * 10 + co;

    float v = 0.0f;
    for (int sb = 0; sb < 16; ++sb) {
        uint4 bm = bmv[sb];
        if ((bm.x | bm.y | bm.z | bm.w) == 0u) {
            if (v != 0.0f) {
                for (int blk = 0; blk < 16 && v != 0.0f; ++blk) {
#pragma unroll
                    for (int j = 0; j < 16; ++j) v *= alpha;
                }
            }
            continue;
        }
        for (int blk = 0; blk < 16; ++blk) {
            uint32_t d = (blk < 4) ? bm.x : (blk < 8) ? bm.y
                       : (blk < 12) ? bm.z : bm.w;
            uint32_t byte = (d >> ((blk & 3) * 8)) & 0xffu;
            if (byte == 0u) {
                if (v != 0.0f) {
#pragma unroll
                    for (int j = 0; j < 16; ++j) v *= alpha;
                }
                continue;
            }
            const int t0 = (sb * 16 + blk) * 16;
            uint4 S[32];
#pragma unroll
            for (int c = 0; c < 32; ++c)
                S[c] = *(const uint4*)(sbase + (size_t)c * T_STEPS + t0);
#pragma unroll
            for (int j = 0; j < 16; ++j) {
                float xv[32];
#pragma unroll
                for (int c = 0; c < 32; ++c) {
                    uint32_t dd = (j < 4) ? S[c].x : (j < 8) ? S[c].y
                                : (j < 12) ? S[c].z : S[c].w;
                    xv[c] = ubf(dd, j & 3);
                }
                float p0 = fmaf(wr[1], xv[1], wr[0] * xv[0]);
                p0 = fmaf(wr[2],  xv[2],  p0); p0 = fmaf(wr[3],  xv[3],  p0);
                p0 = fmaf(wr[4],  xv[4],  p0); p0 = fmaf(wr[5],  xv[5],  p0);
                p0 = fmaf(wr[6],  xv[6],  p0); p0 = fmaf(wr[7],  xv[7],  p0);
                float p1 = fmaf(wr[9], xv[9], wr[8] * xv[8]);
                p1 = fmaf(wr[10], xv[10], p1); p1 = fmaf(wr[11], xv[11], p1);
                p1 = fmaf(wr[12], xv[12], p1); p1 = fmaf(wr[13], xv[13], p1);
                p1 = fmaf(wr[14], xv[14], p1); p1 = fmaf(wr[15], xv[15], p1);
                float p2 = fmaf(wr[17], xv[17], wr[16] * xv[16]);
                p2 = fmaf(wr[18], xv[18], p2); p2 = fmaf(wr[19], xv[19], p2);
                p2 = fmaf(wr[20], xv[20], p2); p2 = fmaf(wr[21], xv[21], p2);
                p2 = fmaf(wr[22], xv[22], p2); p2 = fmaf(wr[23], xv[23], p2);
                float p3 = fmaf(wr[25], xv[25], wr[24] * xv[24]);
                p3 = fmaf(wr[26], xv[26], p3); p3 = fmaf(wr[27], xv[27], p3);
                p3 = fmaf(wr[28], xv[28], p3); p3 = fmaf(wr[29], xv[29], p3);
                p3 = fmaf(wr[30], xv[30], p3); p3 = fmaf(wr[31], xv[31], p3);
                float xs = (p0 + p1) + (p2 + p3);
                float s = lif_step(v, xs, alpha);
                if (active && s != 0.0f) ob[(size_t)(t0 + j) * 10] = s;
            }
        }
    }
}

extern "C" void kernel_launch(void* const* d_in, const int* in_sizes, int n_in,
                              void* d_out, int out_size, void* d_ws, size_t ws_size,
                              hipStream_t stream)
{
    const float* data = (const float*)d_in[0];
    const float* w1   = (const float*)d_in[1];
    const float* w2   = (const float*)d_in[2];
    const float* w3   = (const float*)d_in[3];
    float* out = (float*)d_out;

    // ws layout (48 MiB + 128 KiB + 512 B):
    //   [0, 16M)    s1t  u8 [256][16][4096]  (dense-zeroed only for flagged b)
    //   [16M, 48M)  s2t  u8 [256][32][4096]  (sparse: only bm2-set blocks valid)
    //   [48M, ..)   bm1 64K | bm2 64K | flag1 256 | flag2 256
    uint8_t* ws    = (uint8_t*)d_ws;
    uint8_t* s1t   = ws;
    uint8_t* s2t   = ws + (16u << 20);
    uint8_t* bm1   = ws + (48u << 20);
    uint8_t* bm2   = bm1 + (64u << 10);
    uint8_t* flag1 = bm2 + (64u << 10);
    uint8_t* flag2 = flag1 + 256;

    const float alpha   = expf(-1.0f / 20.0f);
    const float one_m   = 1.0f - alpha;
    const float alpha16 = expf(-16.0f / 20.0f);

    seg1 <<<BATCH,   1024, 0, stream>>>(data, w1, out, s1t, bm1, bm2,
                                        flag1, flag2, alpha, one_m, alpha16);
    scan2<<<BATCH/2,   64, 0, stream>>>(s1t, w2, s2t, bm1, bm2, flag1, flag2,
                                        alpha, one_m);
    scan3<<<BATCH/4,   64, 0, stream>>>(s2t, w3, out, bm2, flag2, alpha, one_m);
}

// Round 12
// 200.247 us; speedup vs baseline: 6.8729x; 1.1214x over previous
//
#include <hip/hip_runtime.h>
#include <stdint.h>
#include <math.h>

#define T_STEPS 4096
#define BATCH   256
#define NB_BLK  256      // T/16 spike blocks per chain == cert segments

// LIF step, threshold=1:  v'=alpha*v+xs; s=max(floor(v'),0); v=v'-s
// Identity: v_new = min(v', fract(v')); s = v' - v_new (exact fp32).
// No-spike step (0<=v'<1 or v'<0) is EXACTLY v = fma(alpha, v, xs).
__device__ __forceinline__ float lif_step(float& v, float xs, float alpha) {
    float vp = fmaf(alpha, v, xs);
    float fr = vp - floorf(vp);
    float vn = fminf(vp, fr);
    float s  = vp - vn;
    v = vn;
    return s;
}

__device__ __forceinline__ float ubf(uint32_t w, int k) {
    return (float)((w >> (k * 8)) & 0xffu);
}

__device__ __forceinline__ float dot16(const float wr[16],
    float4 c0, float4 c1, float4 c2, float4 c3)
{
    float p0 = fmaf(wr[1], c0.y, wr[0] * c0.x);
    p0 = fmaf(wr[2], c0.z, p0);  p0 = fmaf(wr[3], c0.w, p0);
    float p1 = fmaf(wr[5], c1.y, wr[4] * c1.x);
    p1 = fmaf(wr[6], c1.z, p1);  p1 = fmaf(wr[7], c1.w, p1);
    float p2 = fmaf(wr[9], c2.y, wr[8] * c2.x);
    p2 = fmaf(wr[10], c2.z, p2); p2 = fmaf(wr[11], c2.w, p2);
    float p3 = fmaf(wr[13], c3.y, wr[12] * c3.x);
    p3 = fmaf(wr[14], c3.z, p3); p3 = fmaf(wr[15], c3.w, p3);
    return (p0 + p1) + (p2 + p3);
}

// Direct global->LDS DMA, 16 B per lane, no VGPR round-trip (and thus no
// scratch spill — R9/R10/R11 all lost 60-130 MB of HBM to spilled staging).
__device__ __forceinline__ void load_lds16(const float* g, float* l) {
    __builtin_amdgcn_global_load_lds(
        (const __attribute__((address_space(1))) void*)g,
        (__attribute__((address_space(3))) void*)l, 16, 0, 0);
}

// xbuf layout: segment s (16 rows x 16 floats) at float offset s*260
// (1040 B pitch = 1024 B payload + 16 B pad).  A wave's global_load_lds
// fills exactly one segment (64 lanes x 16 B = 1024 B contiguous); the pad
// sits between wave-transfers.  Compute: the 4 distinct sg-addresses in a
// wave are 260 floats apart (bank offset 4) -> the 4 ds_read_b128 hit
// disjoint bank quads (co lanes broadcast) — conflict-free.

// ---------------------------------------------------------------------------
// seg1: one 1024-thread block per batch b = (co 0..15) x (sg 0..63).
//  (a) zero PRIVATE slices of out / bm1 / bm2 / flag2
//  (b) 4 chunks x 64 segments: async global_load_lds staging (wave w stages
//      segments w*4..w*4+3), __syncthreads drains vmcnt, then thread (co,sg)
//      runs the 16-step LINEAR segment response from LDS (bit-matches the
//      serial no-spike fma chain): M0=max acc_j, M1=max(acc_j+alpha^(j+1)),
//      acc_end -> LDS cert arrays [256][16].
//  (c) 16 threads compose vs <- fma(alpha16, vs, acc_end) over 256 segments;
//      certify via convexity: f(vs) <= (1-vs+)*M0 + vs+*M1,
//      vs+ = clamp(vs+1e-3,0,1).  Margin 1e-3 >> fp32 drift.  -> sh_badseg.
//  (d) Repair cert-bad channels (rare): dense-zero s1t[b], recompute y[4096]
//      in parallel into LDS (aliasing xbuf), ONE thread runs the exact
//      chain: pure fma in cert-good segments (exact identity), full
//      lif_step + spike/bm1 writes in bad 16-step segments.
// ---------------------------------------------------------------------------
__global__ __launch_bounds__(1024) void seg1(
    const float* __restrict__ x, const float* __restrict__ w1,
    float* __restrict__ out, uint8_t* __restrict__ s1t,
    uint8_t* __restrict__ bm1, uint8_t* __restrict__ bm2,
    uint8_t* __restrict__ flag1, uint8_t* __restrict__ flag2,
    float alpha, float one_m, float alpha16)
{
    const int tid = threadIdx.x;
    const int b   = blockIdx.x;

    __shared__ __align__(16) float xbuf[16640];          // 65 KiB (chunk / ybuf)
    __shared__ float   sh_end[NB_BLK][16];               // 16 KiB
    __shared__ float   sh_m0[NB_BLK][16];
    __shared__ float   sh_m1[NB_BLK][16];
    __shared__ uint8_t sh_badseg[16][NB_BLK];            // 4 KiB
    __shared__ int     sh_badch;
    __shared__ int     sh_spike;

    // ---- zero per-batch slices --------------------------------------------
    float4* o4 = (float4*)(out + (size_t)b * T_STEPS * 10);   // 10240 float4
    float4 z4 = make_float4(0.f, 0.f, 0.f, 0.f);
#pragma unroll
    for (int i = 0; i < 10; ++i) o4[i * 1024 + tid] = z4;
    if (tid < 16)
        ((uint4*)(bm1 + (size_t)b * NB_BLK))[tid] = make_uint4(0u,0u,0u,0u);
    else if (tid < 32)
        ((uint4*)(bm2 + (size_t)b * NB_BLK))[tid - 16] = make_uint4(0u,0u,0u,0u);
    else if (tid == 32) { flag2[b] = 0; sh_badch = 0; sh_spike = 0; }

    const int co = tid & 15;
    const int sg = tid >> 4;          // 0..63 segment-within-chunk
    const int wv = tid >> 6;          // wave 0..15
    const int ln = tid & 63;          // lane 0..63

    float wr[16];
#pragma unroll
    for (int i = 0; i < 16; ++i) wr[i] = one_m * w1[co * 16 + i];

    const float* xb = x + (size_t)b * T_STEPS * 16;      // 65536 floats

    const int sbase = sg * 260;
    for (int k = 0; k < 4; ++k) {
        __syncthreads();              // xbuf free (previous compute done)
        // async DMA: wave wv stages segments wv*4..wv*4+3 of this chunk
#pragma unroll
        for (int q = 0; q < 4; ++q) {
            int s = wv * 4 + q;
            load_lds16(xb + (size_t)(k * 64 + s) * 256 + ln * 4,
                       &xbuf[s * 260 + ln * 4]);
        }
        __syncthreads();              // drains vmcnt -> xbuf ready

        float acc = 0.0f, m0 = -1e30f, m1 = -1e30f, pw = alpha;
#pragma unroll
        for (int j = 0; j < 16; ++j) {
            const float* rp = &xbuf[sbase + j * 16];
            float4 c0 = *(const float4*)(rp + 0);
            float4 c1 = *(const float4*)(rp + 4);
            float4 c2 = *(const float4*)(rp + 8);
            float4 c3 = *(const float4*)(rp + 12);
            float y = dot16(wr, c0, c1, c2, c3);
            acc = fmaf(alpha, acc, y);
            m0  = fmaxf(m0, acc);
            m1  = fmaxf(m1, acc + pw);
            pw *= alpha;
        }
        const int gs = k * 64 + sg;
        sh_end[gs][co] = acc;
        sh_m0[gs][co]  = m0;
        sh_m1[gs][co]  = m1;
    }
    __syncthreads();

    // ---- serial composition + per-channel/per-segment certification -------
    if (tid < 16) {
        const int c = tid;
        float vs = 0.0f;
        int bad = 0;
#pragma unroll 8
        for (int s = 0; s < NB_BLK; ++s) {
            float vsu = fminf(fmaxf(vs + 1e-3f, 0.0f), 1.0f);
            float bound = fmaf(1.0f - vsu, sh_m0[s][c], vsu * sh_m1[s][c]);
            int sb = (bound >= 0.999f) ? 1 : 0;
            sh_badseg[c][s] = (uint8_t)sb;
            bad |= sb;
            vs = fmaf(alpha16, vs, sh_end[s][c]);
        }
        if (bad) atomicOr(&sh_badch, 1 << c);
    }
    __syncthreads();

    // ---- exact repair for cert-bad channels (rare) ------------------------
    int badmask = sh_badch;
    if (badmask) {
        // dense-zero s1t[b] so scan2 never reads unwritten bytes
        uint4* sz = (uint4*)(s1t + (size_t)b * 16 * T_STEPS);
#pragma unroll
        for (int i = 0; i < 4; ++i) sz[i * 1024 + tid] = make_uint4(0u,0u,0u,0u);
    }
    float* ybuf = xbuf;   // alias: staging done, reuse as y[4096]
    while (badmask) {
        const int c = __ffs(badmask) - 1;
        badmask &= badmask - 1;

        {   // recompute y[b][c][0..4095]: 4 consecutive rows per thread
            float wc[16];
#pragma unroll
            for (int i = 0; i < 16; ++i) wc[i] = one_m * w1[c * 16 + i];
            const float4* xq = (const float4*)xb + (size_t)tid * 16;
#pragma unroll
            for (int kk = 0; kk < 4; ++kk) {
                float4 c0 = xq[kk*4+0], c1 = xq[kk*4+1];
                float4 c2 = xq[kk*4+2], c3 = xq[kk*4+3];
                ybuf[tid * 4 + kk] = dot16(wc, c0, c1, c2, c3);
            }
        }
        __syncthreads();   // ybuf ready; also orders s1t zero before writes

        if (tid == 0) {
            float v = 0.0f;
            int any = 0;
            uint8_t* op  = s1t + ((size_t)b * 16 + c) * T_STEPS;
            uint8_t* bmp = bm1 + (size_t)b * NB_BLK;
            for (int s = 0; s < NB_BLK; ++s) {
                const float* yb = &ybuf[s * 16];
                if (!sh_badseg[c][s]) {
                    // cert-good: no spike possible; lif_step == pure fma here
#pragma unroll
                    for (int j = 0; j < 16; ++j) v = fmaf(alpha, v, yb[j]);
                } else {
                    uint32_t w[4] = {0u,0u,0u,0u};
#pragma unroll
                    for (int j = 0; j < 16; ++j) {
                        float sp = lif_step(v, yb[j], alpha);
                        w[j >> 2] |= ((uint32_t)(int)sp) << ((j & 3) * 8);
                    }
                    if (w[0] | w[1] | w[2] | w[3]) {
                        *(uint4*)(op + s * 16) = make_uint4(w[0], w[1], w[2], w[3]);
                        bmp[s] = 1;
                        any = 1;
                    }
                }
            }
            if (any) sh_spike = 1;
        }
        __syncthreads();
    }
    if (tid == 0) flag1[b] = (uint8_t)sh_spike;
}

// ---------------- layer-2: sparse scan, s1t -> s2t + bitmap2 ----------------
__global__ __launch_bounds__(64) void scan2(const uint8_t* __restrict__ s1t,
        const float* __restrict__ w2, uint8_t* __restrict__ s2t,
        const uint8_t* __restrict__ bm1, uint8_t* __restrict__ bm2,
        const uint8_t* __restrict__ flag1, uint8_t* __restrict__ flag2,
        float alpha, float one_m)
{
    const int tid = threadIdx.x;
    const int co  = tid & 31;
    const int b   = blockIdx.x * 2 + (tid >> 5);
    if (!flag1[b]) return;   // no layer-1 spikes in this batch -> all zero

    float wr[16];
#pragma unroll
    for (int i = 0; i < 16; ++i) wr[i] = one_m * w2[co * 16 + i];

    const uint8_t* sbase = s1t + (size_t)b * 16 * T_STEPS;
    uint4* op = (uint4*)(s2t + ((size_t)b * 32 + co) * T_STEPS);
    const uint4* bmv = (const uint4*)(bm1 + (size_t)b * NB_BLK);
    uint8_t* bm2p = bm2 + (size_t)b * NB_BLK;

    float v = 0.0f;
    for (int sb = 0; sb < 16; ++sb) {
        uint4 bm = bmv[sb];
        if ((bm.x | bm.y | bm.z | bm.w) == 0u) {
            if (v != 0.0f) {
                for (int blk = 0; blk < 16 && v != 0.0f; ++blk) {
#pragma unroll
                    for (int j = 0; j < 16; ++j) v *= alpha;
                }
            }
            continue;
        }
        for (int blk = 0; blk < 16; ++blk) {
            uint32_t d = (blk < 4) ? bm.x : (blk < 8) ? bm.y
                       : (blk < 12) ? bm.z : bm.w;
            uint32_t byte = (d >> ((blk & 3) * 8)) & 0xffu;
            if (byte == 0u) {
                if (v != 0.0f) {
#pragma unroll
                    for (int j = 0; j < 16; ++j) v *= alpha;
                }
                continue;
            }
            const int tb = sb * 16 + blk;
            const int t0 = tb * 16;
            uint4 S[16];
#pragma unroll
            for (int c = 0; c < 16; ++c)
                S[c] = *(const uint4*)(sbase + (size_t)c * T_STEPS + t0);
            uint32_t w[4] = {0u, 0u, 0u, 0u};
#pragma unroll
            for (int j = 0; j < 16; ++j) {
                float xv[16];
#pragma unroll
                for (int c = 0; c < 16; ++c) {
                    uint32_t dd = (j < 4) ? S[c].x : (j < 8) ? S[c].y
                                : (j < 12) ? S[c].z : S[c].w;
                    xv[c] = ubf(dd, j & 3);
                }
                float p0 = fmaf(wr[1], xv[1], wr[0] * xv[0]);
                p0 = fmaf(wr[2], xv[2], p0);   p0 = fmaf(wr[3], xv[3], p0);
                float p1 = fmaf(wr[5], xv[5], wr[4] * xv[4]);
                p1 = fmaf(wr[6], xv[6], p1);   p1 = fmaf(wr[7], xv[7], p1);
                float p2 = fmaf(wr[9], xv[9], wr[8] * xv[8]);
                p2 = fmaf(wr[10], xv[10], p2); p2 = fmaf(wr[11], xv[11], p2);
                float p3 = fmaf(wr[13], xv[13], wr[12] * xv[12]);
                p3 = fmaf(wr[14], xv[14], p3); p3 = fmaf(wr[15], xv[15], p3);
                float xs = (p0 + p1) + (p2 + p3);
                float s = lif_step(v, xs, alpha);
                w[j >> 2] |= ((uint32_t)(int)s) << ((j & 3) * 8);
            }
            op[tb] = make_uint4(w[0], w[1], w[2], w[3]);
            if (w[0] | w[1] | w[2] | w[3]) { bm2p[tb] = 1; flag2[b] = 1; }
        }
    }
}

// ---------------- layer-3: sparse scan, s2t -> out[b,t,10] (pre-zeroed) -----
__global__ __launch_bounds__(64) void scan3(const uint8_t* __restrict__ s2t,
        const float* __restrict__ w3, float* __restrict__ out,
        const uint8_t* __restrict__ bm2, const uint8_t* __restrict__ flag2,
        float alpha, float one_m)
{
    const int tid = threadIdx.x;
    const int co  = tid & 15;           // 10 active
    const int b   = blockIdx.x * 4 + (tid >> 4);
    if (!flag2[b]) return;   // no layer-2 spikes in this batch -> out stays 0
    const bool active = (co < 10);

    float wr[32];
#pragma unroll
    for (int i = 0; i < 32; ++i) wr[i] = active ? (one_m * w3[co * 32 + i]) : 0.0f;

    const uint8_t* sbase = s2t + (size_t)b * 32 * T_STEPS;
    const uint4* bmv = (const uint4*)(bm2 + (size_t)b * NB_BLK);
    float* ob = out + (size_t)b * T_STEPS * 10 + co;

    float v = 0.0f;
    for (int sb = 0; sb < 16; ++sb) {
        uint4 bm = bmv[sb];
        if ((bm.x | bm.y | bm.z | bm.w) == 0u) {
            if (v != 0.0f) {
                for (int blk = 0; blk < 16 && v != 0.0f; ++blk) {
#pragma unroll
                    for (int j = 0; j < 16; ++j) v *= alpha;
                }
            }
            continue;
        }
        for (int blk = 0; blk < 16; ++blk) {
            uint32_t d = (blk < 4) ? bm.x : (blk < 8) ? bm.y
                       : (blk < 12) ? bm.z : bm.w;
            uint32_t byte = (d >> ((blk & 3) * 8)) & 0xffu;
            if (byte == 0u) {
                if (v != 0.0f) {
#pragma unroll
                    for (int j = 0; j < 16; ++j) v *= alpha;
                }
                continue;
            }
            const int t0 = (sb * 16 + blk) * 16;
            uint4 S[32];
#pragma unroll
            for (int c = 0; c < 32; ++c)
                S[c] = *(const uint4*)(sbase + (size_t)c * T_STEPS + t0);
#pragma unroll
            for (int j = 0; j < 16; ++j) {
                float xv[32];
#pragma unroll
                for (int c = 0; c < 32; ++c) {
                    uint32_t dd = (j < 4) ? S[c].x : (j < 8) ? S[c].y
                                : (j < 12) ? S[c].z : S[c].w;
                    xv[c] = ubf(dd, j & 3);
                }
                float p0 = fmaf(wr[1], xv[1], wr[0] * xv[0]);
                p0 = fmaf(wr[2],  xv[2],  p0); p0 = fmaf(wr[3],  xv[3],  p0);
                p0 = fmaf(wr[4],  xv[4],  p0); p0 = fmaf(wr[5],  xv[5],  p0);
                p0 = fmaf(wr[6],  xv[6],  p0); p0 = fmaf(wr[7],  xv[7],  p0);
                float p1 = fmaf(wr[9], xv[9], wr[8] * xv[8]);
                p1 = fmaf(wr[10], xv[10], p1); p1 = fmaf(wr[11], xv[11], p1);
                p1 = fmaf(wr[12], xv[12], p1); p1 = fmaf(wr[13], xv[13], p1);
                p1 = fmaf(wr[14], xv[14], p1); p1 = fmaf(wr[15], xv[15], p1);
                float p2 = fmaf(wr[17], xv[17], wr[16] * xv[16]);
                p2 = fmaf(wr[18], xv[18], p2); p2 = fmaf(wr[19], xv[19], p2);
                p2 = fmaf(wr[20], xv[20], p2); p2 = fmaf(wr[21], xv[21], p2);
                p2 = fmaf(wr[22], xv[22], p2); p2 = fmaf(wr[23], xv[23], p2);
                float p3 = fmaf(wr[25], xv[25], wr[24] * xv[24]);
                p3 = fmaf(wr[26], xv[26], p3); p3 = fmaf(wr[27], xv[27], p3);
                p3 = fmaf(wr[28], xv[28], p3); p3 = fmaf(wr[29], xv[29], p3);
                p3 = fmaf(wr[30], xv[30], p3); p3 = fmaf(wr[31], xv[31], p3);
                float xs = (p0 + p1) + (p2 + p3);
                float s = lif_step(v, xs, alpha);
                if (active && s != 0.0f) ob[(size_t)(t0 + j) * 10] = s;
            }
        }
    }
}

extern "C" void kernel_launch(void* const* d_in, const int* in_sizes, int n_in,
                              void* d_out, int out_size, void* d_ws, size_t ws_size,
                              hipStream_t stream)
{
    const float* data = (const float*)d_in[0];
    const float* w1   = (const float*)d_in[1];
    const float* w2   = (const float*)d_in[2];
    const float* w3   = (const float*)d_in[3];
    float* out = (float*)d_out;

    // ws layout (48 MiB + 128 KiB + 512 B):
    //   [0, 16M)    s1t  u8 [256][16][4096]  (dense-zeroed only for flagged b)
    //   [16M, 48M)  s2t  u8 [256][32][4096]  (sparse: only bm2-set blocks valid)
    //   [48M, ..)   bm1 64K | bm2 64K | flag1 256 | flag2 256
    uint8_t* ws    = (uint8_t*)d_ws;
    uint8_t* s1t   = ws;
    uint8_t* s2t   = ws + (16u << 20);
    uint8_t* bm1   = ws + (48u << 20);
    uint8_t* bm2   = bm1 + (64u << 10);
    uint8_t* flag1 = bm2 + (64u << 10);
    uint8_t* flag2 = flag1 + 256;

    const float alpha   = expf(-1.0f / 20.0f);
    const float one_m   = 1.0f - alpha;
    const float alpha16 = expf(-16.0f / 20.0f);

    seg1 <<<BATCH,   1024, 0, stream>>>(data, w1, out, s1t, bm1, bm2,
                                        flag1, flag2, alpha, one_m, alpha16);
    scan2<<<BATCH/2,   64, 0, stream>>>(s1t, w2, s2t, bm1, bm2, flag1, flag2,
                                        alpha, one_m);
    scan3<<<BATCH/4,   64, 0, stream>>>(s2t, w3, out, bm2, flag2, alpha, one_m);
}

// Round 13
// 195.453 us; speedup vs baseline: 7.0415x; 1.0245x over previous
//
#include <hip/hip_runtime.h>
#include <stdint.h>
#include <math.h>

#define T_STEPS 4096
#define BATCH   256
#define NB_BLK  256      // T/16 spike blocks per chain == cert segments

// s_waitcnt immediates (gfx9 encoding): vmcnt[3:0]|expcnt[6:4]|lgkmcnt[11:8]|vmcnt[15:14]
#define WAIT_VM0   0x0F70   // vmcnt(0), expcnt/lgkmcnt unrestricted
#define WAIT_LGKM0 0xC07F   // lgkmcnt(0), vmcnt/expcnt unrestricted

// LIF step, threshold=1:  v'=alpha*v+xs; s=max(floor(v'),0); v=v'-s
// Identity: v_new = min(v', fract(v')); s = v' - v_new (exact fp32).
// No-spike step (0<=v'<1 or v'<0) is EXACTLY v = fma(alpha, v, xs).
__device__ __forceinline__ float lif_step(float& v, float xs, float alpha) {
    float vp = fmaf(alpha, v, xs);
    float fr = vp - floorf(vp);
    float vn = fminf(vp, fr);
    float s  = vp - vn;
    v = vn;
    return s;
}

__device__ __forceinline__ float ubf(uint32_t w, int k) {
    return (float)((w >> (k * 8)) & 0xffu);
}

__device__ __forceinline__ float dot16(const float wr[16],
    float4 c0, float4 c1, float4 c2, float4 c3)
{
    float p0 = fmaf(wr[1], c0.y, wr[0] * c0.x);
    p0 = fmaf(wr[2], c0.z, p0);  p0 = fmaf(wr[3], c0.w, p0);
    float p1 = fmaf(wr[5], c1.y, wr[4] * c1.x);
    p1 = fmaf(wr[6], c1.z, p1);  p1 = fmaf(wr[7], c1.w, p1);
    float p2 = fmaf(wr[9], c2.y, wr[8] * c2.x);
    p2 = fmaf(wr[10], c2.z, p2); p2 = fmaf(wr[11], c2.w, p2);
    float p3 = fmaf(wr[13], c3.y, wr[12] * c3.x);
    p3 = fmaf(wr[14], c3.z, p3); p3 = fmaf(wr[15], c3.w, p3);
    return (p0 + p1) + (p2 + p3);
}

// Direct global->LDS DMA, 16 B per lane, no VGPR round-trip (R12: killed the
// 60-130 MB scratch-spill traffic of R9-R11).
__device__ __forceinline__ void load_lds16(const float* g, float* l) {
    __builtin_amdgcn_global_load_lds(
        (const __attribute__((address_space(1))) void*)g,
        (__attribute__((address_space(3))) void*)l, 16, 0, 0);
}

// xbuf layout: segment s (16 rows x 16 floats) at float offset s*260
// (1040 B pitch = 1024 B payload + 16 B pad).  A wave's global_load_lds
// fills exactly one segment (64 lanes x 16 B contiguous); the pad sits
// between transfers.  Compute: the 4 distinct sg-addresses in a wave are
// 260 floats apart (bank offset 4) -> the 4 ds_read_b128 hit disjoint bank
// quads (co lanes broadcast) — conflict-free.
//
// KEY (R13): wave wv stages segments wv*4..wv*4+3 and its compute threads
// have sg = tid>>4 in exactly {wv*4..wv*4+3} — LDS regions are WAVE-PRIVATE.
// So the k-loop needs NO __syncthreads at all: wave-local s_waitcnt vmcnt(0)
// after DMA (data landed) and lgkmcnt(0) before re-DMA (reads drained).
// R12's 8 block-wide barriers (each a full vmcnt drain with 1 block/CU) were
// the ~60 us stall.

// ---------------------------------------------------------------------------
__global__ __launch_bounds__(1024) void seg1(
    const float* __restrict__ x, const float* __restrict__ w1,
    float* __restrict__ out, uint8_t* __restrict__ s1t,
    uint8_t* __restrict__ bm1, uint8_t* __restrict__ bm2,
    uint8_t* __restrict__ flag1, uint8_t* __restrict__ flag2,
    float alpha, float one_m, float alpha16)
{
    const int tid = threadIdx.x;
    const int b   = blockIdx.x;

    __shared__ __align__(16) float xbuf[16640];          // 65 KiB (chunk / ybuf)
    __shared__ float   sh_end[NB_BLK][16];               // 16 KiB
    __shared__ float   sh_m0[NB_BLK][16];
    __shared__ float   sh_m1[NB_BLK][16];
    __shared__ uint8_t sh_badseg[16][NB_BLK];            // 4 KiB
    __shared__ int     sh_badch;
    __shared__ int     sh_spike;

    const int co = tid & 15;
    const int sg = tid >> 4;          // 0..63 segment-within-chunk
    const int wv = tid >> 6;          // wave 0..15
    const int ln = tid & 63;          // lane 0..63

    const float* xb = x + (size_t)b * T_STEPS * 16;      // 65536 floats

    // ---- kick off chunk 0 DMA immediately ---------------------------------
#pragma unroll
    for (int q = 0; q < 4; ++q) {
        int s = wv * 4 + q;
        load_lds16(xb + (size_t)s * 256 + ln * 4, &xbuf[s * 260 + ln * 4]);
    }

    // ---- zero per-batch slices (overlaps with chunk-0 DMA) ----------------
    float4* o4 = (float4*)(out + (size_t)b * T_STEPS * 10);   // 10240 float4
    float4 z4 = make_float4(0.f, 0.f, 0.f, 0.f);
#pragma unroll
    for (int i = 0; i < 10; ++i) o4[i * 1024 + tid] = z4;
    if (tid < 16)
        ((uint4*)(bm1 + (size_t)b * NB_BLK))[tid] = make_uint4(0u,0u,0u,0u);
    else if (tid < 32)
        ((uint4*)(bm2 + (size_t)b * NB_BLK))[tid - 16] = make_uint4(0u,0u,0u,0u);
    else if (tid == 32) { flag2[b] = 0; sh_badch = 0; sh_spike = 0; }

    float wr[16];
#pragma unroll
    for (int i = 0; i < 16; ++i) wr[i] = one_m * w1[co * 16 + i];

    const int sbase = sg * 260;
    for (int k = 0; k < 4; ++k) {
        __builtin_amdgcn_s_waitcnt(WAIT_VM0);   // wave-local: chunk k landed

        float acc = 0.0f, m0 = -1e30f, m1 = -1e30f, pw = alpha;
#pragma unroll
        for (int j = 0; j < 16; ++j) {
            const float* rp = &xbuf[sbase + j * 16];
            float4 c0 = *(const float4*)(rp + 0);
            float4 c1 = *(const float4*)(rp + 4);
            float4 c2 = *(const float4*)(rp + 8);
            float4 c3 = *(const float4*)(rp + 12);
            float y = dot16(wr, c0, c1, c2, c3);
            acc = fmaf(alpha, acc, y);
            m0  = fmaxf(m0, acc);
            m1  = fmaxf(m1, acc + pw);
            pw *= alpha;
        }
        const int gs = k * 64 + sg;
        sh_end[gs][co] = acc;
        sh_m0[gs][co]  = m0;
        sh_m1[gs][co]  = m1;

        if (k < 3) {
            // wave-local: all our ds_reads of this chunk are complete
            __builtin_amdgcn_s_waitcnt(WAIT_LGKM0);
#pragma unroll
            for (int q = 0; q < 4; ++q) {
                int s = wv * 4 + q;
                load_lds16(xb + (size_t)((k + 1) * 64 + s) * 256 + ln * 4,
                           &xbuf[s * 260 + ln * 4]);
            }
        }
    }
    __syncthreads();   // all waves' cert entries visible

    // ---- serial composition + per-channel/per-segment certification -------
    if (tid < 16) {
        const int c = tid;
        float vs = 0.0f;
        int bad = 0;
#pragma unroll 8
        for (int s = 0; s < NB_BLK; ++s) {
            float vsu = fminf(fmaxf(vs + 1e-3f, 0.0f), 1.0f);
            float bound = fmaf(1.0f - vsu, sh_m0[s][c], vsu * sh_m1[s][c]);
            int sb = (bound >= 0.999f) ? 1 : 0;
            sh_badseg[c][s] = (uint8_t)sb;
            bad |= sb;
            vs = fmaf(alpha16, vs, sh_end[s][c]);
        }
        if (bad) atomicOr(&sh_badch, 1 << c);
    }
    __syncthreads();

    // ---- exact repair for cert-bad channels (rare) ------------------------
    int badmask = sh_badch;
    if (badmask) {
        // dense-zero s1t[b] so scan2 never reads unwritten bytes
        uint4* sz = (uint4*)(s1t + (size_t)b * 16 * T_STEPS);
#pragma unroll
        for (int i = 0; i < 4; ++i) sz[i * 1024 + tid] = make_uint4(0u,0u,0u,0u);
    }
    float* ybuf = xbuf;   // alias: staging done, reuse as y[4096]
    while (badmask) {
        const int c = __ffs(badmask) - 1;
        badmask &= badmask - 1;

        {   // recompute y[b][c][0..4095]: 4 consecutive rows per thread
            float wc[16];
#pragma unroll
            for (int i = 0; i < 16; ++i) wc[i] = one_m * w1[c * 16 + i];
            const float4* xq = (const float4*)xb + (size_t)tid * 16;
#pragma unroll
            for (int kk = 0; kk < 4; ++kk) {
                float4 c0 = xq[kk*4+0], c1 = xq[kk*4+1];
                float4 c2 = xq[kk*4+2], c3 = xq[kk*4+3];
                ybuf[tid * 4 + kk] = dot16(wc, c0, c1, c2, c3);
            }
        }
        __syncthreads();   // ybuf ready; also orders s1t zero before writes

        if (tid == 0) {
            float v = 0.0f;
            int any = 0;
            uint8_t* op  = s1t + ((size_t)b * 16 + c) * T_STEPS;
            uint8_t* bmp = bm1 + (size_t)b * NB_BLK;
            for (int s = 0; s < NB_BLK; ++s) {
                const float* yb = &ybuf[s * 16];
                if (!sh_badseg[c][s]) {
                    // cert-good: no spike possible; lif_step == pure fma here
#pragma unroll
                    for (int j = 0; j < 16; ++j) v = fmaf(alpha, v, yb[j]);
                } else {
                    uint32_t w[4] = {0u,0u,0u,0u};
#pragma unroll
                    for (int j = 0; j < 16; ++j) {
                        float sp = lif_step(v, yb[j], alpha);
                        w[j >> 2] |= ((uint32_t)(int)sp) << ((j & 3) * 8);
                    }
                    if (w[0] | w[1] | w[2] | w[3]) {
                        *(uint4*)(op + s * 16) = make_uint4(w[0], w[1], w[2], w[3]);
                        bmp[s] = 1;
                        any = 1;
                    }
                }
            }
            if (any) sh_spike = 1;
        }
        __syncthreads();
    }
    if (tid == 0) flag1[b] = (uint8_t)sh_spike;
}

// ---------------- layer-2: sparse scan, s1t -> s2t + bitmap2 ----------------
__global__ __launch_bounds__(64) void scan2(const uint8_t* __restrict__ s1t,
        const float* __restrict__ w2, uint8_t* __restrict__ s2t,
        const uint8_t* __restrict__ bm1, uint8_t* __restrict__ bm2,
        const uint8_t* __restrict__ flag1, uint8_t* __restrict__ flag2,
        float alpha, float one_m)
{
    const int tid = threadIdx.x;
    const int co  = tid & 31;
    const int b   = blockIdx.x * 2 + (tid >> 5);
    if (!flag1[b]) return;   // no layer-1 spikes in this batch -> all zero

    float wr[16];
#pragma unroll
    for (int i = 0; i < 16; ++i) wr[i] = one_m * w2[co * 16 + i];

    const uint8_t* sbase = s1t + (size_t)b * 16 * T_STEPS;
    uint4* op = (uint4*)(s2t + ((size_t)b * 32 + co) * T_STEPS);
    const uint4* bmv = (const uint4*)(bm1 + (size_t)b * NB_BLK);
    uint8_t* bm2p = bm2 + (size_t)b * NB_BLK;

    float v = 0.0f;
    for (int sb = 0; sb < 16; ++sb) {
        uint4 bm = bmv[sb];
        if ((bm.x | bm.y | bm.z | bm.w) == 0u) {
            if (v != 0.0f) {
                for (int blk = 0; blk < 16 && v != 0.0f; ++blk) {
#pragma unroll
                    for (int j = 0; j < 16; ++j) v *= alpha;
                }
            }
            continue;
        }
        for (int blk = 0; blk < 16; ++blk) {
            uint32_t d = (blk < 4) ? bm.x : (blk < 8) ? bm.y
                       : (blk < 12) ? bm.z : bm.w;
            uint32_t byte = (d >> ((blk & 3) * 8)) & 0xffu;
            if (byte == 0u) {
                if (v != 0.0f) {
#pragma unroll
                    for (int j = 0; j < 16; ++j) v *= alpha;
                }
                continue;
            }
            const int tb = sb * 16 + blk;
            const int t0 = tb * 16;
            uint4 S[16];
#pragma unroll
            for (int c = 0; c < 16; ++c)
                S[c] = *(const uint4*)(sbase + (size_t)c * T_STEPS + t0);
            uint32_t w[4] = {0u, 0u, 0u, 0u};
#pragma unroll
            for (int j = 0; j < 16; ++j) {
                float xv[16];
#pragma unroll
                for (int c = 0; c < 16; ++c) {
                    uint32_t dd = (j < 4) ? S[c].x : (j < 8) ? S[c].y
                                : (j < 12) ? S[c].z : S[c].w;
                    xv[c] = ubf(dd, j & 3);
                }
                float p0 = fmaf(wr[1], xv[1], wr[0] * xv[0]);
                p0 = fmaf(wr[2], xv[2], p0);   p0 = fmaf(wr[3], xv[3], p0);
                float p1 = fmaf(wr[5], xv[5], wr[4] * xv[4]);
                p1 = fmaf(wr[6], xv[6], p1);   p1 = fmaf(wr[7], xv[7], p1);
                float p2 = fmaf(wr[9], xv[9], wr[8] * xv[8]);
                p2 = fmaf(wr[10], xv[10], p2); p2 = fmaf(wr[11], xv[11], p2);
                float p3 = fmaf(wr[13], xv[13], wr[12] * xv[12]);
                p3 = fmaf(wr[14], xv[14], p3); p3 = fmaf(wr[15], xv[15], p3);
                float xs = (p0 + p1) + (p2 + p3);
                float s = lif_step(v, xs, alpha);
                w[j >> 2] |= ((uint32_t)(int)s) << ((j & 3) * 8);
            }
            op[tb] = make_uint4(w[0], w[1], w[2], w[3]);
            if (w[0] | w[1] | w[2] | w[3]) { bm2p[tb] = 1; flag2[b] = 1; }
        }
    }
}

// ---------------- layer-3: sparse scan, s2t -> out[b,t,10] (pre-zeroed) -----
__global__ __launch_bounds__(64) void scan3(const uint8_t* __restrict__ s2t,
        const float* __restrict__ w3, float* __restrict__ out,
        const uint8_t* __restrict__ bm2, const uint8_t* __restrict__ flag2,
        float alpha, float one_m)
{
    const int tid = threadIdx.x;
    const int co  = tid & 15;           // 10 active
    const int b   = blockIdx.x * 4 + (tid >> 4);
    if (!flag2[b]) return;   // no layer-2 spikes in this batch -> out stays 0
    const bool active = (co < 10);

    float wr[32];
#pragma unroll
    for (int i = 0; i < 32; ++i) wr[i] = active ? (one_m * w3[co * 32 + i]) : 0.0f;

    const uint8_t* sbase = s2t + (size_t)b * 32 * T_STEPS;
    const uint4* bmv = (const uint4*)(bm2 + (size_t)b * NB_BLK);
    float* ob = out + (size_t)b * T_STEPS * 10 + co;

    float v = 0.0f;
    for (int sb = 0; sb < 16; ++sb) {
        uint4 bm = bmv[sb];
        if ((bm.x | bm.y | bm.z | bm.w) == 0u) {
            if (v != 0.0f) {
                for (int blk = 0; blk < 16 && v != 0.0f; ++blk) {
#pragma unroll
                    for (int j = 0; j < 16; ++j) v *= alpha;
                }
            }
            continue;
        }
        for (int blk = 0; blk < 16; ++blk) {
            uint32_t d = (blk < 4) ? bm.x : (blk < 8) ? bm.y
                       : (blk < 12) ? bm.z : bm.w;
            uint32_t byte = (d >> ((blk & 3) * 8)) & 0xffu;
            if (byte == 0u) {
                if (v != 0.0f) {
#pragma unroll
                    for (int j = 0; j < 16; ++j) v *= alpha;
                }
                continue;
            }
            const int t0 = (sb * 16 + blk) * 16;
            uint4 S[32];
#pragma unroll
            for (int c = 0; c < 32; ++c)
                S[c] = *(const uint4*)(sbase + (size_t)c * T_STEPS + t0);
#pragma unroll
            for (int j = 0; j < 16; ++j) {
                float xv[32];
#pragma unroll
                for (int c = 0; c < 32; ++c) {
                    uint32_t dd = (j < 4) ? S[c].x : (j < 8) ? S[c].y
                                : (j < 12) ? S[c].z : S[c].w;
                    xv[c] = ubf(dd, j & 3);
                }
                float p0 = fmaf(wr[1], xv[1], wr[0] * xv[0]);
                p0 = fmaf(wr[2],  xv[2],  p0); p0 = fmaf(wr[3],  xv[3],  p0);
                p0 = fmaf(wr[4],  xv[4],  p0); p0 = fmaf(wr[5],  xv[5],  p0);
                p0 = fmaf(wr[6],  xv[6],  p0); p0 = fmaf(wr[7],  xv[7],  p0);
                float p1 = fmaf(wr[9], xv[9], wr[8] * xv[8]);
                p1 = fmaf(wr[10], xv[10], p1); p1 = fmaf(wr[11], xv[11], p1);
                p1 = fmaf(wr[12], xv[12], p1); p1 = fmaf(wr[13], xv[13], p1);
                p1 = fmaf(wr[14], xv[14], p1); p1 = fmaf(wr[15], xv[15], p1);
                float p2 = fmaf(wr[17], xv[17], wr[16] * xv[16]);
                p2 = fmaf(wr[18], xv[18], p2); p2 = fmaf(wr[19], xv[19], p2);
                p2 = fmaf(wr[20], xv[20], p2); p2 = fmaf(wr[21], xv[21], p2);
                p2 = fmaf(wr[22], xv[22], p2); p2 = fmaf(wr[23], xv[23], p2);
                float p3 = fmaf(wr[25], xv[25], wr[24] * xv[24]);
                p3 = fmaf(wr[26], xv[26], p3); p3 = fmaf(wr[27], xv[27], p3);
                p3 = fmaf(wr[28], xv[28], p3); p3 = fmaf(wr[29], xv[29], p3);
                p3 = fmaf(wr[30], xv[30], p3); p3 = fmaf(wr[31], xv[31], p3);
                float xs = (p0 + p1) + (p2 + p3);
                float s = lif_step(v, xs, alpha);
                if (active && s != 0.0f) ob[(size_t)(t0 + j) * 10] = s;
            }
        }
    }
}

extern "C" void kernel_launch(void* const* d_in, const int* in_sizes, int n_in,
                              void* d_out, int out_size, void* d_ws, size_t ws_size,
                              hipStream_t stream)
{
    const float* data = (const float*)d_in[0];
    const float* w1   = (const float*)d_in[1];
    const float* w2   = (const float*)d_in[2];
    const float* w3   = (const float*)d_in[3];
    float* out = (float*)d_out;

    // ws layout (48 MiB + 128 KiB + 512 B):
    //   [0, 16M)    s1t  u8 [256][16][4096]  (dense-zeroed only for flagged b)
    //   [16M, 48M)  s2t  u8 [256][32][4096]  (sparse: only bm2-set blocks valid)
    //   [48M, ..)   bm1 64K | bm2 64K | flag1 256 | flag2 256
    uint8_t* ws    = (uint8_t*)d_ws;
    uint8_t* s1t   = ws;
    uint8_t* s2t   = ws + (16u << 20);
    uint8_t* bm1   = ws + (48u << 20);
    uint8_t* bm2   = bm1 + (64u << 10);
    uint8_t* flag1 = bm2 + (64u << 10);
    uint8_t* flag2 = flag1 + 256;

    const float alpha   = expf(-1.0f / 20.0f);
    const float one_m   = 1.0f - alpha;
    const float alpha16 = expf(-16.0f / 20.0f);

    seg1 <<<BATCH,   1024, 0, stream>>>(data, w1, out, s1t, bm1, bm2,
                                        flag1, flag2, alpha, one_m, alpha16);
    scan2<<<BATCH/2,   64, 0, stream>>>(s1t, w2, s2t, bm1, bm2, flag1, flag2,
                                        alpha, one_m);
    scan3<<<BATCH/4,   64, 0, stream>>>(s2t, w3, out, bm2, flag2, alpha, one_m);
}